// Round 3
// baseline (2228.326 us; speedup 1.0000x reference)
//
#include <hip/hip_runtime.h>

#define NN 30000
#define EE 480000
#define HH 256
#define TT 4
#define GG 64
#define CC 10
#define MP 30080   // 235 * 128, padded rows

typedef unsigned short u16;
typedef unsigned int u32;
typedef short short8 __attribute__((ext_vector_type(8)));
typedef float f32x4 __attribute__((ext_vector_type(4)));

// ---------- helpers ----------
__device__ __forceinline__ u16 f2bf(float x) {
    u32 u = __float_as_uint(x);
    u32 r = (u + 0x7FFFu + ((u >> 16) & 1u)) >> 16;   // RNE
    return (u16)r;
}
__device__ __forceinline__ float bf2f(u16 h) {
    return __uint_as_float(((u32)h) << 16);
}
__device__ __forceinline__ u32 encf(float x) {       // order-preserving float->uint
    u32 u = __float_as_uint(x);
    return (u & 0x80000000u) ? ~u : (u | 0x80000000u);
}
__device__ __forceinline__ float decf(u32 e) {
    u32 u = (e & 0x80000000u) ? (e ^ 0x80000000u) : ~e;
    return __uint_as_float(u);
}
__device__ __forceinline__ void gl_lds16(const void* g, void* l) {
    __builtin_amdgcn_global_load_lds(
        (const __attribute__((address_space(1))) void*)g,
        (__attribute__((address_space(3))) void*)l, 16, 0, 0);
}

// ---------- conversion / packing kernels ----------
__global__ void k_convert(const float* __restrict__ in, u16* __restrict__ hi,
                          u16* __restrict__ lo, int n) {
    int i = blockIdx.x * 256 + threadIdx.x;
    if (i < n) {
        float v = in[i];
        u16 h = f2bf(v);
        hi[i] = h;
        lo[i] = f2bf(v - bf2f(h));
    }
}

// combined GRU weight wG [1024 x 512]:
//   rows 0..511 : [w_ih_rz | w_hh_rz]
//   rows 512..767 : [w_ih_n | 0]
//   rows 768..1023: [0 | w_hh_n]
__global__ void k_pack_G(const float* __restrict__ w_ih, const float* __restrict__ w_hh,
                         u16* __restrict__ hi, u16* __restrict__ lo) {
    int i = blockIdx.x * 256 + threadIdx.x;   // over 1024*512
    int j = i >> 9, k = i & 511;
    float v;
    if (j < 512)       v = (k < 256) ? w_ih[j * 256 + k] : w_hh[j * 256 + (k - 256)];
    else if (j < 768)  v = (k < 256) ? w_ih[j * 256 + k] : 0.f;
    else               v = (k >= 256) ? w_hh[(j - 256) * 256 + (k - 256)] : 0.f;
    u16 h = f2bf(v);
    hi[i] = h;
    lo[i] = f2bf(v - bf2f(h));
}

__global__ void k_bias(const float* __restrict__ b_ih, const float* __restrict__ b_hh,
                       float* __restrict__ bG) {
    int j = threadIdx.x + blockIdx.x * 256;
    if (j < 512)       bG[j] = b_ih[j] + b_hh[j];
    else if (j < 768)  bG[j] = b_ih[j];
    else if (j < 1024) bG[j] = b_hh[j - 256];
}

// h state -> ah cols 256..511 (hi/lo). Padded rows = 0.
__global__ __launch_bounds__(256) void k_feat(const float* __restrict__ feat,
                                              u16* __restrict__ ahHi, u16* __restrict__ ahLo) {
    int n = blockIdx.x, c = threadIdx.x;
    float v = (n < NN) ? feat[(size_t)n * HH + c] : 0.f;
    size_t i = (size_t)n * 512 + 256 + c;
    u16 hb = f2bf(v);
    ahHi[i] = hb;
    ahLo[i] = f2bf(v - bf2f(hb));
}

// ---------- CSR build ----------
__global__ void k_count(const int* __restrict__ dst, int* __restrict__ cnt) {
    int e = blockIdx.x * 256 + threadIdx.x;
    if (e < EE) atomicAdd(&cnt[dst[e]], 1);
}

__global__ __launch_bounds__(1024) void k_scan(const int* __restrict__ cnt,
                                               int* __restrict__ rowptr,
                                               int* __restrict__ cur) {
    __shared__ int buf[1024];
    __shared__ int carry;
    int tid = threadIdx.x;
    if (tid == 0) carry = 0;
    __syncthreads();
    for (int base = 0; base < NN; base += 1024) {
        int x = (base + tid < NN) ? cnt[base + tid] : 0;
        buf[tid] = x;
        __syncthreads();
        for (int ofs = 1; ofs < 1024; ofs <<= 1) {
            int v = (tid >= ofs) ? buf[tid - ofs] : 0;
            __syncthreads();
            buf[tid] += v;
            __syncthreads();
        }
        int excl = buf[tid] - x + carry;
        if (base + tid < NN) { rowptr[base + tid] = excl; cur[base + tid] = excl; }
        int total = buf[1023];
        __syncthreads();
        if (tid == 0) carry += total;
        __syncthreads();
    }
    if (tid == 0) rowptr[NN] = EE;
}

__global__ void k_fill(const int* __restrict__ src, const int* __restrict__ dst,
                       const int* __restrict__ et, int* __restrict__ cur,
                       int* __restrict__ colpk) {
    int e = blockIdx.x * 256 + threadIdx.x;
    if (e < EE) {
        int pos = atomicAdd(&cur[dst[e]], 1);
        colpk[pos] = (et[e] << 16) | src[e];
    }
}

// ---------- split-bf16 MFMA GEMM: C[128y x 128x] = A[. x K] * B[. x K]^T + bias ----------
// 3-term split: Ahi*Bhi + Ahi*Blo + Alo*Bhi  (~fp16-or-better accuracy, fp32 accum)
__global__ __launch_bounds__(256) void gemm_split(
    const u16* __restrict__ Ahi, const u16* __restrict__ Alo, int lda,
    const u16* __restrict__ Bhi, const u16* __restrict__ Blo, int ldb,
    const float* __restrict__ bias, float* __restrict__ C, int ldc, int KT) {
    __shared__ u16 sAh[4096], sAl[4096], sBh[4096], sBl[4096];
    const int tid = threadIdx.x;
    const int lane = tid & 63;
    const int wv = tid >> 6;
    const int wr = wv >> 1, wc = wv & 1;
    const int m0 = blockIdx.y * 128, n0 = blockIdx.x * 128;

    const int ldRow = tid >> 2;
    const int ldK = (tid & 3) * 8;
    const u16* aH = Ahi + (size_t)(m0 + ldRow) * lda + ldK;
    const u16* aL = Alo + (size_t)(m0 + ldRow) * lda + ldK;
    const u16* bH = Bhi + (size_t)(n0 + ldRow) * ldb + ldK;
    const u16* bL = Blo + (size_t)(n0 + ldRow) * ldb + ldK;
    const size_t rstepA = (size_t)64 * lda;
    const size_t rstepB = (size_t)64 * ldb;

    const int wbyte = (tid & ~63) * 16;   // wave-uniform LDS base (lane0 of wave)
    char* dAh = (char*)sAh + wbyte;
    char* dAl = (char*)sAl + wbyte;
    char* dBh = (char*)sBh + wbyte;
    char* dBl = (char*)sBl + wbyte;

    f32x4 acc[4][4];
#pragma unroll
    for (int i = 0; i < 4; i++)
#pragma unroll
        for (int j = 0; j < 4; j++) acc[i][j] = {0.f, 0.f, 0.f, 0.f};

    const int fr = lane & 15;
    const int q8 = (lane >> 4) * 8;

    for (int kt = 0; kt < KT; ++kt) {
        const int k0 = kt * 32;
        __syncthreads();
        gl_lds16(aH + k0, dAh);
        gl_lds16(aH + k0 + rstepA, dAh + 4096);
        gl_lds16(aL + k0, dAl);
        gl_lds16(aL + k0 + rstepA, dAl + 4096);
        gl_lds16(bH + k0, dBh);
        gl_lds16(bH + k0 + rstepB, dBh + 4096);
        gl_lds16(bL + k0, dBl);
        gl_lds16(bL + k0 + rstepB, dBl + 4096);
        __syncthreads();

        short8 bh[4], bl[4];
#pragma unroll
        for (int j = 0; j < 4; j++) {
            int brow = wc * 64 + j * 16 + fr;
            bh[j] = *(const short8*)&sBh[brow * 32 + q8];
            bl[j] = *(const short8*)&sBl[brow * 32 + q8];
        }
#pragma unroll
        for (int i = 0; i < 4; i++) {
            int arow = wr * 64 + i * 16 + fr;
            short8 ah = *(const short8*)&sAh[arow * 32 + q8];
            short8 al = *(const short8*)&sAl[arow * 32 + q8];
#pragma unroll
            for (int j = 0; j < 4; j++) {
                acc[i][j] = __builtin_amdgcn_mfma_f32_16x16x32_bf16(ah, bh[j], acc[i][j], 0, 0, 0);
                acc[i][j] = __builtin_amdgcn_mfma_f32_16x16x32_bf16(ah, bl[j], acc[i][j], 0, 0, 0);
                acc[i][j] = __builtin_amdgcn_mfma_f32_16x16x32_bf16(al, bh[j], acc[i][j], 0, 0, 0);
            }
        }
    }

    // C/D layout (verified m89/m91): col = lane&15, row = (lane>>4)*4 + reg
    const int lr = (lane >> 4) * 4;
    const int lc = lane & 15;
#pragma unroll
    for (int j = 0; j < 4; j++) {
        const int col = n0 + wc * 64 + j * 16 + lc;
        const float bj = bias[col];
#pragma unroll
        for (int i = 0; i < 4; i++) {
            const int rb = m0 + wr * 64 + i * 16 + lr;
#pragma unroll
            for (int r = 0; r < 4; r++)
                C[(size_t)(rb + r) * ldc + col] = acc[i][j][r] + bj;
        }
    }
}

// ---------- per-dst aggregation (pull via CSR, no atomics) -> ah cols 0..255 ----------
__global__ __launch_bounds__(256) void k_agg(const float* __restrict__ Wh,
                                             const int* __restrict__ rowptr,
                                             const int* __restrict__ colpk,
                                             u16* __restrict__ ahHi, u16* __restrict__ ahLo) {
    int n = blockIdx.x, c = threadIdx.x;
    float s = 0.f;
    if (n < NN) {
        int e0 = rowptr[n], e1 = rowptr[n + 1];
        for (int e = e0; e < e1; ++e) {
            int pk = colpk[e];
            int sr = pk & 0xFFFF;
            int t = pk >> 16;
            s += Wh[(size_t)sr * 1024 + t * 256 + c];
        }
    }
    size_t i = (size_t)n * 512 + c;
    u16 hb = f2bf(s);
    ahHi[i] = hb;
    ahLo[i] = f2bf(s - bf2f(hb));
}

// ---------- GRU cell elementwise: G = [rsum(256)|zsum(256)|i_n(256)|h_n(256)] ----------
__global__ __launch_bounds__(256) void k_gru(const float* __restrict__ G,
                                             u16* __restrict__ ahHi, u16* __restrict__ ahLo) {
    int n = blockIdx.x, c = threadIdx.x;
    size_t b = (size_t)n * 1024 + c;
    float rsum = G[b], zsum = G[b + 256], inn = G[b + 512], hn = G[b + 768];
    float r = 1.f / (1.f + expf(-rsum));
    float z = 1.f / (1.f + expf(-zsum));
    float nn = tanhf(inn + r * hn);
    size_t i = (size_t)n * 512 + 256 + c;
    float hv = bf2f(ahHi[i]) + bf2f(ahLo[i]);
    float o = (1.f - z) * nn + z * hv;
    u16 hb = f2bf(o);
    ahHi[i] = hb;
    ahLo[i] = f2bf(o - bf2f(hb));
}

// ---------- tail: elu + BN stats (h2 = raw elu output, f32) ----------
__global__ __launch_bounds__(256) void k_elu_stats(const u16* __restrict__ ahHi,
                                                   const u16* __restrict__ ahLo,
                                                   float* __restrict__ h2,
                                                   float* __restrict__ bnsum,
                                                   float* __restrict__ bnsq) {
    int c = threadIdx.x;
    int r0 = blockIdx.x * 128;
    int r1 = min(r0 + 128, NN);
    float s = 0.f, q = 0.f;
    for (int n = r0; n < r1; ++n) {
        size_t i = (size_t)n * 512 + 256 + c;
        float x = bf2f(ahHi[i]) + bf2f(ahLo[i]);
        float e = x > 0.f ? x : expm1f(x);
        h2[(size_t)n * HH + c] = e;
        s += e;
        q += e * e;
    }
    atomicAdd(&bnsum[c], s);
    atomicAdd(&bnsq[c], q);
}

// ---------- fold BN affine into gate weights: wp[0..255], wp[256]=const ----------
__global__ __launch_bounds__(256) void k_prep(const float* __restrict__ bnsum,
                                              const float* __restrict__ bnsq,
                                              const float* __restrict__ gamma,
                                              const float* __restrict__ beta,
                                              const float* __restrict__ gate_w,
                                              const float* __restrict__ gate_b,
                                              float* __restrict__ wp) {
    __shared__ float red[256];
    int c = threadIdx.x;
    float mu = bnsum[c] * (1.f / NN);
    float var = bnsq[c] * (1.f / NN) - mu * mu;
    float rs = rsqrtf(var + 1e-5f);
    float gm = gamma[c], w = gate_w[c];
    wp[c] = rs * gm * w;
    red[c] = (beta[c] - mu * rs * gm) * w;
    __syncthreads();
    for (int st = 128; st > 0; st >>= 1) {
        if (c < st) red[c] += red[c + st];
        __syncthreads();
    }
    if (c == 0) wp[256] = red[0] + gate_b[0];
}

// ---------- gate score: wave-per-node dot(h2_raw, wp) + const; segment max ----------
__global__ __launch_bounds__(256) void k_gate(const float* __restrict__ h2,
                                              const float* __restrict__ wp,
                                              const int* __restrict__ n2g,
                                              float* __restrict__ gate,
                                              u32* __restrict__ gmaxenc) {
    int lane = threadIdx.x & 63, wv = threadIdx.x >> 6;
    int n = blockIdx.x * 4 + wv;                       // 7500 * 4 = 30000 exact
    float4 v = ((const float4*)(h2 + (size_t)n * HH))[lane];
    float4 w = ((const float4*)wp)[lane];
    float s = v.x * w.x + v.y * w.y + v.z * w.z + v.w * w.w;
#pragma unroll
    for (int off = 32; off; off >>= 1) s += __shfl_down(s, off);
    if (lane == 0) {
        float gt = s + wp[256];
        gate[n] = gt;
        atomicMax(&gmaxenc[n2g[n]], encf(gt));
    }
}

// ---------- exp + denom ----------
__global__ void k_expden(float* __restrict__ gate, const int* __restrict__ n2g,
                         const u32* __restrict__ gmaxenc, float* __restrict__ denom) {
    int n = blockIdx.x * 256 + threadIdx.x;
    if (n < NN) {
        int g = n2g[n];
        float e = expf(gate[n] - decf(gmaxenc[g]));
        gate[n] = e;
        atomicAdd(&denom[g], e);
    }
}

// ---------- attention pooling over RAW h2 (n2g sorted; flush on graph change) ----------
__global__ __launch_bounds__(256) void k_pool(const float* __restrict__ h2,
                                              const float* __restrict__ gate,
                                              const float* __restrict__ denom,
                                              const int* __restrict__ n2g,
                                              float* __restrict__ h_g) {
    int c = threadIdx.x;
    int r0 = blockIdx.x * 128, r1 = min(r0 + 128, NN);
    int gcur = -1;
    float accv = 0.f, inv = 0.f;
    for (int n = r0; n < r1; ++n) {
        int g = n2g[n];
        if (g != gcur) {
            if (gcur >= 0) atomicAdd(&h_g[gcur * HH + c], accv);
            gcur = g;
            accv = 0.f;
            inv = 1.f / denom[g];
        }
        accv += gate[n] * inv * h2[(size_t)n * HH + c];
    }
    if (gcur >= 0) atomicAdd(&h_g[gcur * HH + c], accv);
}

// ---------- classifier (applies BN affine to pooled vector) ----------
__global__ __launch_bounds__(256) void k_cls(const float* __restrict__ h_g,
                                             const float* __restrict__ bnsum,
                                             const float* __restrict__ bnsq,
                                             const float* __restrict__ gamma,
                                             const float* __restrict__ beta,
                                             const float* __restrict__ W1,
                                             const float* __restrict__ b1,
                                             const float* __restrict__ W2,
                                             const float* __restrict__ b2,
                                             float* __restrict__ out) {
    __shared__ float hg[256];
    __shared__ float x1[128];
    int g = blockIdx.x, tid = threadIdx.x;
    float mu = bnsum[tid] * (1.f / NN);
    float var = bnsq[tid] * (1.f / NN) - mu * mu;
    hg[tid] = (h_g[g * HH + tid] - mu) * rsqrtf(var + 1e-5f) * gamma[tid] + beta[tid];
    __syncthreads();
    if (tid < 128) {
        const float* w = W1 + tid * 256;
        float s = b1[tid];
#pragma unroll 8
        for (int c = 0; c < 256; ++c) s += hg[c] * w[c];
        x1[tid] = fmaxf(s, 0.f);
    }
    __syncthreads();
    if (tid < 10) {
        const float* w = W2 + tid * 128;
        float s = b2[tid];
        for (int j = 0; j < 128; ++j) s += x1[j] * w[j];
        out[g * CC + tid] = s;
    }
}

// =======================================================================
extern "C" void kernel_launch(void* const* d_in, const int* in_sizes, int n_in,
                              void* d_out, int out_size, void* d_ws, size_t ws_size,
                              hipStream_t stream) {
    const float* feat  = (const float*)d_in[0];
    const int*   src   = (const int*)d_in[1];
    const int*   dst   = (const int*)d_in[2];
    const int*   etype = (const int*)d_in[3];
    const int*   n2g   = (const int*)d_in[4];
    const float* W_msg = (const float*)d_in[5];
    const float* b_msg = (const float*)d_in[6];
    const float* w_ih  = (const float*)d_in[7];
    const float* w_hh  = (const float*)d_in[8];
    const float* b_ih  = (const float*)d_in[9];
    const float* b_hh  = (const float*)d_in[10];
    const float* bn_g  = (const float*)d_in[11];
    const float* bn_b  = (const float*)d_in[12];
    const float* gatew = (const float*)d_in[13];
    const float* gateb = (const float*)d_in[14];
    const float* W1    = (const float*)d_in[15];
    const float* b1    = (const float*)d_in[16];
    const float* W2    = (const float*)d_in[17];
    const float* b2    = (const float*)d_in[18];
    float* out = (float*)d_out;

    char* ws = (char*)d_ws;
    size_t off = 0;
    auto alloc = [&](size_t bytes) -> char* {
        char* p = ws + off;
        off += (bytes + 255) & ~(size_t)255;
        return p;
    };

    // zero zone (single memset): cnt | bnsum | bnsq | denom | gmaxenc | h_g
    const size_t ZZ = (size_t)(NN + 256 + 256 + 64 + 64 + GG * HH) * 4;
    char* zz = alloc(ZZ);
    int*   cnt     = (int*)zz;
    float* bnsum   = (float*)(zz + (size_t)NN * 4);
    float* bnsq    = bnsum + 256;
    float* denom   = bnsq + 256;
    u32*   gmaxenc = (u32*)(denom + 64);
    float* h_g     = (float*)(gmaxenc + 64);

    int* rowptr = (int*)alloc((NN + 1) * 4);
    int* cur    = (int*)alloc(NN * 4);
    int* colpk  = (int*)alloc((size_t)EE * 4);
    float* gate = (float*)alloc(NN * 4);
    float* wp   = (float*)alloc(260 * 4);
    float* bG   = (float*)alloc(1024 * 4);

    // interleaved node state: cols 0..255 = a, cols 256..511 = h (hi/lo bf16)
    u16* ahHi = (u16*)alloc((size_t)MP * 512 * 2);
    u16* ahLo = (u16*)alloc((size_t)MP * 512 * 2);

    u16* wmsgHi = (u16*)alloc((size_t)1024 * 256 * 2);
    u16* wmsgLo = (u16*)alloc((size_t)1024 * 256 * 2);
    u16* wGHi   = (u16*)alloc((size_t)1024 * 512 * 2);
    u16* wGLo   = (u16*)alloc((size_t)1024 * 512 * 2);

    // big region [MP x 1024] f32: Wh, then G, then h2
    float* big = (float*)alloc((size_t)MP * 1024 * 4);
    float* Wh = big;
    float* G  = big;
    float* h2 = big;

    hipMemsetAsync(zz, 0, ZZ, stream);

    k_convert<<<1024, 256, 0, stream>>>(W_msg, wmsgHi, wmsgLo, 1024 * 256);
    k_pack_G<<<2048, 256, 0, stream>>>(w_ih, w_hh, wGHi, wGLo);
    k_bias<<<4, 256, 0, stream>>>(b_ih, b_hh, bG);
    k_feat<<<MP, 256, 0, stream>>>(feat, ahHi, ahLo);

    k_count<<<(EE + 255) / 256, 256, 0, stream>>>(dst, cnt);
    k_scan<<<1, 1024, 0, stream>>>(cnt, rowptr, cur);
    k_fill<<<(EE + 255) / 256, 256, 0, stream>>>(src, dst, etype, cur, colpk);

    for (int s = 0; s < 5; ++s) {
        // Wh = h * W_msg^T  [MP x 1024]
        gemm_split<<<dim3(8, MP / 128), 256, 0, stream>>>(
            ahHi + 256, ahLo + 256, 512, wmsgHi, wmsgLo, 256, b_msg, Wh, 1024, 8);
        k_agg<<<MP, 256, 0, stream>>>(Wh, rowptr, colpk, ahHi, ahLo);
        // G = [a|h] * wG^T  (K=512, N=1024): rsum | zsum | i_n | h_n
        gemm_split<<<dim3(8, MP / 128), 256, 0, stream>>>(
            ahHi, ahLo, 512, wGHi, wGLo, 512, bG, G, 1024, 16);
        k_gru<<<MP, 256, 0, stream>>>(G, ahHi, ahLo);
    }

    k_elu_stats<<<235, 256, 0, stream>>>(ahHi, ahLo, h2, bnsum, bnsq);
    k_prep<<<1, 256, 0, stream>>>(bnsum, bnsq, bn_g, bn_b, gatew, gateb, wp);
    k_gate<<<NN / 4, 256, 0, stream>>>(h2, wp, n2g, gate, gmaxenc);
    k_expden<<<(NN + 255) / 256, 256, 0, stream>>>(gate, n2g, gmaxenc, denom);
    k_pool<<<235, 256, 0, stream>>>(h2, gate, denom, n2g, h_g);
    k_cls<<<GG, 256, 0, stream>>>(h_g, bnsum, bnsq, bn_g, bn_b, W1, b1, W2, b2, out);

    (void)in_sizes; (void)n_in; (void)out_size; (void)ws_size;
}

// Round 4
// 1863.185 us; speedup vs baseline: 1.1960x; 1.1960x over previous
//
#include <hip/hip_runtime.h>

#define NN 30000
#define EE 480000
#define HH 256
#define TT 4
#define GG 64
#define CC 10
#define MP 30080   // 235 * 128, padded rows

typedef unsigned short u16;
typedef unsigned int u32;
typedef short short8 __attribute__((ext_vector_type(8)));
typedef float f32x4 __attribute__((ext_vector_type(4)));

// ---------- helpers ----------
__device__ __forceinline__ u16 f2bf(float x) {
    u32 u = __float_as_uint(x);
    u32 r = (u + 0x7FFFu + ((u >> 16) & 1u)) >> 16;   // RNE
    return (u16)r;
}
__device__ __forceinline__ float bf2f(u16 h) {
    return __uint_as_float(((u32)h) << 16);
}
__device__ __forceinline__ u32 encf(float x) {       // order-preserving float->uint
    u32 u = __float_as_uint(x);
    return (u & 0x80000000u) ? ~u : (u | 0x80000000u);
}
__device__ __forceinline__ float decf(u32 e) {
    u32 u = (e & 0x80000000u) ? (e ^ 0x80000000u) : ~e;
    return __uint_as_float(u);
}
__device__ __forceinline__ void gl_lds16(const void* g, void* l) {
    __builtin_amdgcn_global_load_lds(
        (const __attribute__((address_space(1))) void*)g,
        (__attribute__((address_space(3))) void*)l, 16, 0, 0);
}

// ---------- conversion / packing kernels ----------
__global__ void k_convert(const float* __restrict__ in, u16* __restrict__ hi,
                          u16* __restrict__ lo, int n) {
    int i = blockIdx.x * 256 + threadIdx.x;
    if (i < n) {
        float v = in[i];
        u16 h = f2bf(v);
        hi[i] = h;
        lo[i] = f2bf(v - bf2f(h));
    }
}

// wrz[j][k] = k<256 ? w_ih[j][k] : w_hh[j][k-256]   (j<512: r,z rows)
__global__ void k_pack_rz(const float* __restrict__ w_ih, const float* __restrict__ w_hh,
                          u16* __restrict__ hi, u16* __restrict__ lo) {
    int i = blockIdx.x * 256 + threadIdx.x;   // over 512*512
    int j = i >> 9, k = i & 511;
    float v = (k < 256) ? w_ih[j * 256 + k] : w_hh[j * 256 + (k - 256)];
    u16 h = f2bf(v);
    hi[i] = h;
    lo[i] = f2bf(v - bf2f(h));
}

__global__ void k_brz(const float* __restrict__ b_ih, const float* __restrict__ b_hh,
                      float* __restrict__ brz) {
    int j = threadIdx.x + blockIdx.x * 256;
    if (j < 512) brz[j] = b_ih[j] + b_hh[j];
}

// h state -> ah cols 256..511 (hi/lo). Padded rows = 0.
__global__ __launch_bounds__(256) void k_feat(const float* __restrict__ feat,
                                              u16* __restrict__ ahHi, u16* __restrict__ ahLo) {
    int n = blockIdx.x, c = threadIdx.x;
    float v = (n < NN) ? feat[(size_t)n * HH + c] : 0.f;
    size_t i = (size_t)n * 512 + 256 + c;
    u16 hb = f2bf(v);
    ahHi[i] = hb;
    ahLo[i] = f2bf(v - bf2f(hb));
}

// ---------- CSR build ----------
__global__ void k_count(const int* __restrict__ dst, int* __restrict__ cnt) {
    int e = blockIdx.x * 256 + threadIdx.x;
    if (e < EE) atomicAdd(&cnt[dst[e]], 1);
}

__global__ __launch_bounds__(1024) void k_scan(const int* __restrict__ cnt,
                                               int* __restrict__ rowptr,
                                               int* __restrict__ cur) {
    __shared__ int buf[1024];
    __shared__ int carry;
    int tid = threadIdx.x;
    if (tid == 0) carry = 0;
    __syncthreads();
    for (int base = 0; base < NN; base += 1024) {
        int x = (base + tid < NN) ? cnt[base + tid] : 0;
        buf[tid] = x;
        __syncthreads();
        for (int ofs = 1; ofs < 1024; ofs <<= 1) {
            int v = (tid >= ofs) ? buf[tid - ofs] : 0;
            __syncthreads();
            buf[tid] += v;
            __syncthreads();
        }
        int excl = buf[tid] - x + carry;
        if (base + tid < NN) { rowptr[base + tid] = excl; cur[base + tid] = excl; }
        int total = buf[1023];
        __syncthreads();
        if (tid == 0) carry += total;
        __syncthreads();
    }
    if (tid == 0) rowptr[NN] = EE;
}

__global__ void k_fill(const int* __restrict__ src, const int* __restrict__ dst,
                       const int* __restrict__ et, int* __restrict__ cur,
                       int* __restrict__ colpk) {
    int e = blockIdx.x * 256 + threadIdx.x;
    if (e < EE) {
        int pos = atomicAdd(&cur[dst[e]], 1);
        colpk[pos] = (et[e] << 16) | src[e];
    }
}

// ---------- split-bf16 MFMA GEMM: C[128y x 128x] = A[. x K] * B[. x K]^T + bias ----------
// 3-term split: Ahi*Bhi + Ahi*Blo + Alo*Bhi  (~fp16-or-better accuracy, fp32 accum)
__global__ __launch_bounds__(256) void gemm_split(
    const u16* __restrict__ Ahi, const u16* __restrict__ Alo, int lda,
    const u16* __restrict__ Bhi, const u16* __restrict__ Blo, int ldb,
    const float* __restrict__ bias, float* __restrict__ C, int ldc, int KT) {
    __shared__ u16 sAh[4096], sAl[4096], sBh[4096], sBl[4096];
    const int tid = threadIdx.x;
    const int lane = tid & 63;
    const int wv = tid >> 6;
    const int wr = wv >> 1, wc = wv & 1;
    const int m0 = blockIdx.y * 128, n0 = blockIdx.x * 128;

    const int ldRow = tid >> 2;
    const int ldK = (tid & 3) * 8;
    const u16* aH = Ahi + (size_t)(m0 + ldRow) * lda + ldK;
    const u16* aL = Alo + (size_t)(m0 + ldRow) * lda + ldK;
    const u16* bH = Bhi + (size_t)(n0 + ldRow) * ldb + ldK;
    const u16* bL = Blo + (size_t)(n0 + ldRow) * ldb + ldK;
    const size_t rstepA = (size_t)64 * lda;
    const size_t rstepB = (size_t)64 * ldb;

    const int wbyte = (tid & ~63) * 16;   // wave-uniform LDS base (lane0 of wave)
    char* dAh = (char*)sAh + wbyte;
    char* dAl = (char*)sAl + wbyte;
    char* dBh = (char*)sBh + wbyte;
    char* dBl = (char*)sBl + wbyte;

    f32x4 acc[4][4];
#pragma unroll
    for (int i = 0; i < 4; i++)
#pragma unroll
        for (int j = 0; j < 4; j++) acc[i][j] = {0.f, 0.f, 0.f, 0.f};

    const int fr = lane & 15;
    const int q8 = (lane >> 4) * 8;

    for (int kt = 0; kt < KT; ++kt) {
        const int k0 = kt * 32;
        __syncthreads();
        gl_lds16(aH + k0, dAh);
        gl_lds16(aH + k0 + rstepA, dAh + 4096);
        gl_lds16(aL + k0, dAl);
        gl_lds16(aL + k0 + rstepA, dAl + 4096);
        gl_lds16(bH + k0, dBh);
        gl_lds16(bH + k0 + rstepB, dBh + 4096);
        gl_lds16(bL + k0, dBl);
        gl_lds16(bL + k0 + rstepB, dBl + 4096);
        __syncthreads();

        short8 bh[4], bl[4];
#pragma unroll
        for (int j = 0; j < 4; j++) {
            int brow = wc * 64 + j * 16 + fr;
            bh[j] = *(const short8*)&sBh[brow * 32 + q8];
            bl[j] = *(const short8*)&sBl[brow * 32 + q8];
        }
#pragma unroll
        for (int i = 0; i < 4; i++) {
            int arow = wr * 64 + i * 16 + fr;
            short8 ah = *(const short8*)&sAh[arow * 32 + q8];
            short8 al = *(const short8*)&sAl[arow * 32 + q8];
#pragma unroll
            for (int j = 0; j < 4; j++) {
                acc[i][j] = __builtin_amdgcn_mfma_f32_16x16x32_bf16(ah, bh[j], acc[i][j], 0, 0, 0);
                acc[i][j] = __builtin_amdgcn_mfma_f32_16x16x32_bf16(ah, bl[j], acc[i][j], 0, 0, 0);
                acc[i][j] = __builtin_amdgcn_mfma_f32_16x16x32_bf16(al, bh[j], acc[i][j], 0, 0, 0);
            }
        }
    }

    // C/D layout (verified m89/m91): col = lane&15, row = (lane>>4)*4 + reg
    const int lr = (lane >> 4) * 4;
    const int lc = lane & 15;
#pragma unroll
    for (int j = 0; j < 4; j++) {
        const int col = n0 + wc * 64 + j * 16 + lc;
        const float bj = bias[col];
#pragma unroll
        for (int i = 0; i < 4; i++) {
            const int rb = m0 + wr * 64 + i * 16 + lr;
#pragma unroll
            for (int r = 0; r < 4; r++)
                C[(size_t)(rb + r) * ldc + col] = acc[i][j][r] + bj;
        }
    }
}

// ---------- per-dst aggregation (pull via CSR, no atomics) -> ah cols 0..255 ----------
__global__ __launch_bounds__(256) void k_agg(const float* __restrict__ Wh,
                                             const int* __restrict__ rowptr,
                                             const int* __restrict__ colpk,
                                             u16* __restrict__ ahHi, u16* __restrict__ ahLo) {
    int n = blockIdx.x, c = threadIdx.x;
    float s = 0.f;
    if (n < NN) {
        int e0 = rowptr[n], e1 = rowptr[n + 1];
        for (int e = e0; e < e1; ++e) {
            int pk = colpk[e];
            int sr = pk & 0xFFFF;
            int t = pk >> 16;
            s += Wh[(size_t)sr * 1024 + t * 256 + c];
        }
    }
    size_t i = (size_t)n * 512 + c;
    u16 hb = f2bf(s);
    ahHi[i] = hb;
    ahLo[i] = f2bf(s - bf2f(hb));
}

// ---------- GRU cell elementwise: G = [rsum(256)|zsum(256)|i_n(256)|h_n(256)] ----------
__global__ __launch_bounds__(256) void k_gru(const float* __restrict__ G,
                                             u16* __restrict__ ahHi, u16* __restrict__ ahLo) {
    int n = blockIdx.x, c = threadIdx.x;
    size_t b = (size_t)n * 1024 + c;
    float rsum = G[b], zsum = G[b + 256], inn = G[b + 512], hn = G[b + 768];
    float r = 1.f / (1.f + expf(-rsum));
    float z = 1.f / (1.f + expf(-zsum));
    float nn = tanhf(inn + r * hn);
    size_t i = (size_t)n * 512 + 256 + c;
    float hv = bf2f(ahHi[i]) + bf2f(ahLo[i]);
    float o = (1.f - z) * nn + z * hv;
    u16 hb = f2bf(o);
    ahHi[i] = hb;
    ahLo[i] = f2bf(o - bf2f(hb));
}

// ---------- tail: elu + BN stats (h2 = raw elu output, f32) ----------
__global__ __launch_bounds__(256) void k_elu_stats(const u16* __restrict__ ahHi,
                                                   const u16* __restrict__ ahLo,
                                                   float* __restrict__ h2,
                                                   float* __restrict__ bnsum,
                                                   float* __restrict__ bnsq) {
    int c = threadIdx.x;
    int r0 = blockIdx.x * 128;
    int r1 = min(r0 + 128, NN);
    float s = 0.f, q = 0.f;
    for (int n = r0; n < r1; ++n) {
        size_t i = (size_t)n * 512 + 256 + c;
        float x = bf2f(ahHi[i]) + bf2f(ahLo[i]);
        float e = x > 0.f ? x : expm1f(x);
        h2[(size_t)n * HH + c] = e;
        s += e;
        q += e * e;
    }
    atomicAdd(&bnsum[c], s);
    atomicAdd(&bnsq[c], q);
}

// ---------- fold BN affine into gate weights: wp[0..255], wp[256]=const ----------
__global__ __launch_bounds__(256) void k_prep(const float* __restrict__ bnsum,
                                              const float* __restrict__ bnsq,
                                              const float* __restrict__ gamma,
                                              const float* __restrict__ beta,
                                              const float* __restrict__ gate_w,
                                              const float* __restrict__ gate_b,
                                              float* __restrict__ wp) {
    __shared__ float red[256];
    int c = threadIdx.x;
    float mu = bnsum[c] * (1.f / NN);
    float var = bnsq[c] * (1.f / NN) - mu * mu;
    float rs = rsqrtf(var + 1e-5f);
    float gm = gamma[c], w = gate_w[c];
    wp[c] = rs * gm * w;
    red[c] = (beta[c] - mu * rs * gm) * w;
    __syncthreads();
    for (int st = 128; st > 0; st >>= 1) {
        if (c < st) red[c] += red[c + st];
        __syncthreads();
    }
    if (c == 0) wp[256] = red[0] + gate_b[0];
}

// ---------- gate score: wave dots, LDS-staged segment max (few global atomics) ----------
__global__ __launch_bounds__(256) void k_gate(const float* __restrict__ h2,
                                              const float* __restrict__ wp,
                                              const int* __restrict__ n2g,
                                              float* __restrict__ gate,
                                              u32* __restrict__ gmaxenc) {
    __shared__ u32 smax[64];
    int tid = threadIdx.x;
    if (tid < 64) smax[tid] = 0;
    __syncthreads();
    int lane = tid & 63, wv = tid >> 6;
    int base = blockIdx.x * 128 + wv * 32;       // each wave: 32 consecutive nodes
    float4 w = ((const float4*)wp)[lane];
    float wc = wp[256];
    for (int k = 0; k < 32; ++k) {
        int n = base + k;
        if (n >= NN) break;
        float4 v = ((const float4*)(h2 + (size_t)n * HH))[lane];
        float s = v.x * w.x + v.y * w.y + v.z * w.z + v.w * w.w;
#pragma unroll
        for (int off = 32; off; off >>= 1) s += __shfl_down(s, off);
        if (lane == 0) {
            float gt = s + wc;
            gate[n] = gt;
            atomicMax(&smax[n2g[n]], encf(gt));
        }
    }
    __syncthreads();
    if (tid < 64 && smax[tid]) atomicMax(&gmaxenc[tid], smax[tid]);
}

// ---------- exp + denom (LDS-staged segment sum) ----------
__global__ __launch_bounds__(256) void k_expden(float* __restrict__ gate,
                                                const int* __restrict__ n2g,
                                                const u32* __restrict__ gmaxenc,
                                                float* __restrict__ denom) {
    __shared__ float ssum[64];
    int tid = threadIdx.x;
    if (tid < 64) ssum[tid] = 0.f;
    __syncthreads();
    int n = blockIdx.x * 256 + tid;
    if (n < NN) {
        int g = n2g[n];
        float e = expf(gate[n] - decf(gmaxenc[g]));
        gate[n] = e;
        atomicAdd(&ssum[g], e);
    }
    __syncthreads();
    if (tid < 64 && ssum[tid] != 0.f) atomicAdd(&denom[tid], ssum[tid]);
}

// ---------- attention pooling over RAW h2 (n2g sorted; flush on graph change) ----------
__global__ __launch_bounds__(256) void k_pool(const float* __restrict__ h2,
                                              const float* __restrict__ gate,
                                              const float* __restrict__ denom,
                                              const int* __restrict__ n2g,
                                              float* __restrict__ h_g) {
    int c = threadIdx.x;
    int r0 = blockIdx.x * 128, r1 = min(r0 + 128, NN);
    int gcur = -1;
    float accv = 0.f, inv = 0.f;
    for (int n = r0; n < r1; ++n) {
        int g = n2g[n];
        if (g != gcur) {
            if (gcur >= 0) atomicAdd(&h_g[gcur * HH + c], accv);
            gcur = g;
            accv = 0.f;
            inv = 1.f / denom[g];
        }
        accv += gate[n] * inv * h2[(size_t)n * HH + c];
    }
    if (gcur >= 0) atomicAdd(&h_g[gcur * HH + c], accv);
}

// ---------- classifier (applies BN affine to pooled vector) ----------
__global__ __launch_bounds__(256) void k_cls(const float* __restrict__ h_g,
                                             const float* __restrict__ bnsum,
                                             const float* __restrict__ bnsq,
                                             const float* __restrict__ gamma,
                                             const float* __restrict__ beta,
                                             const float* __restrict__ W1,
                                             const float* __restrict__ b1,
                                             const float* __restrict__ W2,
                                             const float* __restrict__ b2,
                                             float* __restrict__ out) {
    __shared__ float hg[256];
    __shared__ float x1[128];
    int g = blockIdx.x, tid = threadIdx.x;
    float mu = bnsum[tid] * (1.f / NN);
    float var = bnsq[tid] * (1.f / NN) - mu * mu;
    hg[tid] = (h_g[g * HH + tid] - mu) * rsqrtf(var + 1e-5f) * gamma[tid] + beta[tid];
    __syncthreads();
    if (tid < 128) {
        const float* w = W1 + tid * 256;
        float s = b1[tid];
#pragma unroll 8
        for (int c = 0; c < 256; ++c) s += hg[c] * w[c];
        x1[tid] = fmaxf(s, 0.f);
    }
    __syncthreads();
    if (tid < 10) {
        const float* w = W2 + tid * 128;
        float s = b2[tid];
        for (int j = 0; j < 128; ++j) s += x1[j] * w[j];
        out[g * CC + tid] = s;
    }
}

// =======================================================================
extern "C" void kernel_launch(void* const* d_in, const int* in_sizes, int n_in,
                              void* d_out, int out_size, void* d_ws, size_t ws_size,
                              hipStream_t stream) {
    const float* feat  = (const float*)d_in[0];
    const int*   src   = (const int*)d_in[1];
    const int*   dst   = (const int*)d_in[2];
    const int*   etype = (const int*)d_in[3];
    const int*   n2g   = (const int*)d_in[4];
    const float* W_msg = (const float*)d_in[5];
    const float* b_msg = (const float*)d_in[6];
    const float* w_ih  = (const float*)d_in[7];
    const float* w_hh  = (const float*)d_in[8];
    const float* b_ih  = (const float*)d_in[9];
    const float* b_hh  = (const float*)d_in[10];
    const float* bn_g  = (const float*)d_in[11];
    const float* bn_b  = (const float*)d_in[12];
    const float* gatew = (const float*)d_in[13];
    const float* gateb = (const float*)d_in[14];
    const float* W1    = (const float*)d_in[15];
    const float* b1    = (const float*)d_in[16];
    const float* W2    = (const float*)d_in[17];
    const float* b2    = (const float*)d_in[18];
    float* out = (float*)d_out;

    char* ws = (char*)d_ws;
    size_t off = 0;
    auto alloc = [&](size_t bytes) -> char* {
        char* p = ws + off;
        off += (bytes + 255) & ~(size_t)255;
        return p;
    };

    // zero zone (single memset): cnt | bnsum | bnsq | denom | gmaxenc | h_g
    const size_t ZZ = (size_t)(NN + 256 + 256 + 64 + 64 + GG * HH) * 4;
    char* zz = alloc(ZZ);
    int*   cnt     = (int*)zz;
    float* bnsum   = (float*)(zz + (size_t)NN * 4);
    float* bnsq    = bnsum + 256;
    float* denom   = bnsq + 256;
    u32*   gmaxenc = (u32*)(denom + 64);
    float* h_g     = (float*)(gmaxenc + 64);

    int* rowptr = (int*)alloc((NN + 1) * 4);
    int* cur    = (int*)alloc(NN * 4);
    int* colpk  = (int*)alloc((size_t)EE * 4);
    float* gate = (float*)alloc(NN * 4);
    float* wp   = (float*)alloc(260 * 4);

    // interleaved node state: cols 0..255 = a, cols 256..511 = h (hi/lo bf16)
    u16* ahHi = (u16*)alloc((size_t)MP * 512 * 2);
    u16* ahLo = (u16*)alloc((size_t)MP * 512 * 2);

    u16* wmsgHi = (u16*)alloc((size_t)1024 * 256 * 2);
    u16* wmsgLo = (u16*)alloc((size_t)1024 * 256 * 2);
    u16* wrzHi  = (u16*)alloc((size_t)512 * 512 * 2);
    u16* wrzLo  = (u16*)alloc((size_t)512 * 512 * 2);
    u16* winHi  = (u16*)alloc((size_t)256 * 256 * 2);
    u16* winLo  = (u16*)alloc((size_t)256 * 256 * 2);
    u16* whnHi  = (u16*)alloc((size_t)256 * 256 * 2);
    u16* whnLo  = (u16*)alloc((size_t)256 * 256 * 2);
    float* brz  = (float*)alloc(512 * 4);

    // big region [MP x 1024] f32: Wh, then G = [rsum|zsum|i_n|h_n], then h2
    float* big = (float*)alloc((size_t)MP * 1024 * 4);
    float* Wh = big;
    float* G  = big;
    float* h2 = big;

    hipMemsetAsync(zz, 0, ZZ, stream);

    k_convert<<<1024, 256, 0, stream>>>(W_msg, wmsgHi, wmsgLo, 1024 * 256);
    k_convert<<<256, 256, 0, stream>>>(w_ih + 512 * 256, winHi, winLo, 256 * 256);
    k_convert<<<256, 256, 0, stream>>>(w_hh + 512 * 256, whnHi, whnLo, 256 * 256);
    k_pack_rz<<<1024, 256, 0, stream>>>(w_ih, w_hh, wrzHi, wrzLo);
    k_brz<<<2, 256, 0, stream>>>(b_ih, b_hh, brz);
    k_feat<<<MP, 256, 0, stream>>>(feat, ahHi, ahLo);

    k_count<<<(EE + 255) / 256, 256, 0, stream>>>(dst, cnt);
    k_scan<<<1, 1024, 0, stream>>>(cnt, rowptr, cur);
    k_fill<<<(EE + 255) / 256, 256, 0, stream>>>(src, dst, etype, cur, colpk);

    for (int s = 0; s < 5; ++s) {
        // Wh = h * W_msg^T  [MP x 1024]
        gemm_split<<<dim3(8, MP / 128), 256, 0, stream>>>(
            ahHi + 256, ahLo + 256, 512, wmsgHi, wmsgLo, 256, b_msg, Wh, 1024, 8);
        k_agg<<<MP, 256, 0, stream>>>(Wh, rowptr, colpk, ahHi, ahLo);
        // rsum|zsum = [a|h] * wrz^T (K=512) -> G cols 0..511
        gemm_split<<<dim3(4, MP / 128), 256, 0, stream>>>(
            ahHi, ahLo, 512, wrzHi, wrzLo, 512, brz, G, 1024, 16);
        // i_n = a * w_in^T (K=256) -> G cols 512..767
        gemm_split<<<dim3(2, MP / 128), 256, 0, stream>>>(
            ahHi, ahLo, 512, winHi, winLo, 256, b_ih + 512, G + 512, 1024, 8);
        // h_n = h * w_hn^T (K=256) -> G cols 768..1023
        gemm_split<<<dim3(2, MP / 128), 256, 0, stream>>>(
            ahHi + 256, ahLo + 256, 512, whnHi, whnLo, 256, b_hh + 512, G + 768, 1024, 8);
        k_gru<<<MP, 256, 0, stream>>>(G, ahHi, ahLo);
    }

    k_elu_stats<<<235, 256, 0, stream>>>(ahHi, ahLo, h2, bnsum, bnsq);
    k_prep<<<1, 256, 0, stream>>>(bnsum, bnsq, bn_g, bn_b, gatew, gateb, wp);
    k_gate<<<235, 256, 0, stream>>>(h2, wp, n2g, gate, gmaxenc);
    k_expden<<<(NN + 255) / 256, 256, 0, stream>>>(gate, n2g, gmaxenc, denom);
    k_pool<<<235, 256, 0, stream>>>(h2, gate, denom, n2g, h_g);
    k_cls<<<GG, 256, 0, stream>>>(h_g, bnsum, bnsq, bn_g, bn_b, W1, b1, W2, b2, out);

    (void)in_sizes; (void)n_in; (void)out_size; (void)ws_size;
}

// Round 5
// 1455.494 us; speedup vs baseline: 1.5310x; 1.2801x over previous
//
#include <hip/hip_runtime.h>

#define NN 30000
#define EE 480000
#define HH 256
#define TT 4
#define GG 64
#define CC 10
#define MP 30080   // 235 * 128, padded rows

typedef unsigned short u16;
typedef unsigned int u32;
typedef _Float16 f16;
typedef f16 half8 __attribute__((ext_vector_type(8)));
typedef float f32x4 __attribute__((ext_vector_type(4)));

// ---------- helpers ----------
__device__ __forceinline__ u32 encf(float x) {       // order-preserving float->uint
    u32 u = __float_as_uint(x);
    return (u & 0x80000000u) ? ~u : (u | 0x80000000u);
}
__device__ __forceinline__ float decf(u32 e) {
    u32 u = (e & 0x80000000u) ? (e ^ 0x80000000u) : ~e;
    return __uint_as_float(u);
}
__device__ __forceinline__ void gl_lds16(const void* g, void* l) {
    __builtin_amdgcn_global_load_lds(
        (const __attribute__((address_space(1))) void*)g,
        (__attribute__((address_space(3))) void*)l, 16, 0, 0);
}

// ---------- conversion / packing kernels ----------
__global__ void k_convert(const float* __restrict__ in, f16* __restrict__ o, int n) {
    int i = blockIdx.x * 256 + threadIdx.x;
    if (i < n) o[i] = (f16)in[i];
}

// wrz[j][k] = k<256 ? w_ih[j][k] : w_hh[j][k-256]   (j<512: r,z rows)
__global__ void k_pack_rz(const float* __restrict__ w_ih, const float* __restrict__ w_hh,
                          f16* __restrict__ o) {
    int i = blockIdx.x * 256 + threadIdx.x;   // over 512*512
    int j = i >> 9, k = i & 511;
    o[i] = (f16)((k < 256) ? w_ih[j * 256 + k] : w_hh[j * 256 + (k - 256)]);
}

__global__ void k_brz(const float* __restrict__ b_ih, const float* __restrict__ b_hh,
                      float* __restrict__ brz) {
    int j = threadIdx.x + blockIdx.x * 256;
    if (j < 512) brz[j] = b_ih[j] + b_hh[j];
}

// h state -> ah cols 256..511. Padded rows = 0.
__global__ __launch_bounds__(256) void k_feat(const float* __restrict__ feat,
                                              f16* __restrict__ ah) {
    int n = blockIdx.x, c = threadIdx.x;
    float v = (n < NN) ? feat[(size_t)n * HH + c] : 0.f;
    ah[(size_t)n * 512 + 256 + c] = (f16)v;
}

// ---------- CSR build ----------
__global__ void k_count(const int* __restrict__ dst, int* __restrict__ cnt) {
    int e = blockIdx.x * 256 + threadIdx.x;
    if (e < EE) atomicAdd(&cnt[dst[e]], 1);
}

__global__ __launch_bounds__(1024) void k_scan(const int* __restrict__ cnt,
                                               int* __restrict__ rowptr,
                                               int* __restrict__ cur) {
    __shared__ int buf[1024];
    __shared__ int carry;
    int tid = threadIdx.x;
    if (tid == 0) carry = 0;
    __syncthreads();
    for (int base = 0; base < NN; base += 1024) {
        int x = (base + tid < NN) ? cnt[base + tid] : 0;
        buf[tid] = x;
        __syncthreads();
        for (int ofs = 1; ofs < 1024; ofs <<= 1) {
            int v = (tid >= ofs) ? buf[tid - ofs] : 0;
            __syncthreads();
            buf[tid] += v;
            __syncthreads();
        }
        int excl = buf[tid] - x + carry;
        if (base + tid < NN) { rowptr[base + tid] = excl; cur[base + tid] = excl; }
        int total = buf[1023];
        __syncthreads();
        if (tid == 0) carry += total;
        __syncthreads();
    }
    if (tid == 0) rowptr[NN] = EE;
}

__global__ void k_fill(const int* __restrict__ src, const int* __restrict__ dst,
                       const int* __restrict__ et, int* __restrict__ cur,
                       int* __restrict__ colpk) {
    int e = blockIdx.x * 256 + threadIdx.x;
    if (e < EE) {
        int pos = atomicAdd(&cur[dst[e]], 1);
        colpk[pos] = (et[e] << 16) | src[e];
    }
}

// ---------- fp16 MFMA GEMM: C[128y x 128x] = A[. x K] * B[. x K]^T + bias ----------
__global__ __launch_bounds__(256) void gemm_f16(
    const f16* __restrict__ A, int lda,
    const f16* __restrict__ B, int ldb,
    const float* __restrict__ bias, float* __restrict__ C, int ldc, int KT) {
    __shared__ f16 sA[4096], sB[4096];           // 128 rows x 32 k
    const int tid = threadIdx.x;
    const int lane = tid & 63;
    const int wv = tid >> 6;
    const int wr = wv >> 1, wc = wv & 1;
    const int m0 = blockIdx.y * 128, n0 = blockIdx.x * 128;

    const int ldRow = tid >> 2;
    const int ldK = (tid & 3) * 8;
    const f16* aP = A + (size_t)(m0 + ldRow) * lda + ldK;
    const f16* bP = B + (size_t)(n0 + ldRow) * ldb + ldK;
    const size_t rstepA = (size_t)64 * lda;
    const size_t rstepB = (size_t)64 * ldb;

    const int wbyte = (tid & ~63) * 16;   // wave-uniform LDS base (lane0 of wave)
    char* dA = (char*)sA + wbyte;
    char* dB = (char*)sB + wbyte;

    f32x4 acc[4][4];
#pragma unroll
    for (int i = 0; i < 4; i++)
#pragma unroll
        for (int j = 0; j < 4; j++) acc[i][j] = {0.f, 0.f, 0.f, 0.f};

    const int fr = lane & 15;
    const int q8 = (lane >> 4) * 8;

    for (int kt = 0; kt < KT; ++kt) {
        const int k0 = kt * 32;
        __syncthreads();
        gl_lds16(aP + k0, dA);
        gl_lds16(aP + k0 + rstepA, dA + 4096);
        gl_lds16(bP + k0, dB);
        gl_lds16(bP + k0 + rstepB, dB + 4096);
        __syncthreads();

        half8 bh[4];
#pragma unroll
        for (int j = 0; j < 4; j++) {
            int brow = wc * 64 + j * 16 + fr;
            bh[j] = *(const half8*)&sB[brow * 32 + q8];
        }
#pragma unroll
        for (int i = 0; i < 4; i++) {
            int arow = wr * 64 + i * 16 + fr;
            half8 ah = *(const half8*)&sA[arow * 32 + q8];
#pragma unroll
            for (int j = 0; j < 4; j++)
                acc[i][j] = __builtin_amdgcn_mfma_f32_16x16x32_f16(ah, bh[j], acc[i][j], 0, 0, 0);
        }
    }

    // C/D layout (verified m89/m91): col = lane&15, row = (lane>>4)*4 + reg
    const int lr = (lane >> 4) * 4;
    const int lc = lane & 15;
#pragma unroll
    for (int j = 0; j < 4; j++) {
        const int col = n0 + wc * 64 + j * 16 + lc;
        const float bj = bias[col];
#pragma unroll
        for (int i = 0; i < 4; i++) {
            const int rb = m0 + wr * 64 + i * 16 + lr;
#pragma unroll
            for (int r = 0; r < 4; r++)
                C[(size_t)(rb + r) * ldc + col] = acc[i][j][r] + bj;
        }
    }
}

// same GEMM but fp16 output (for Wh)
__global__ __launch_bounds__(256) void gemm_f16_o16(
    const f16* __restrict__ A, int lda,
    const f16* __restrict__ B, int ldb,
    const float* __restrict__ bias, f16* __restrict__ C, int ldc, int KT) {
    __shared__ f16 sA[4096], sB[4096];
    const int tid = threadIdx.x;
    const int lane = tid & 63;
    const int wv = tid >> 6;
    const int wr = wv >> 1, wc = wv & 1;
    const int m0 = blockIdx.y * 128, n0 = blockIdx.x * 128;

    const int ldRow = tid >> 2;
    const int ldK = (tid & 3) * 8;
    const f16* aP = A + (size_t)(m0 + ldRow) * lda + ldK;
    const f16* bP = B + (size_t)(n0 + ldRow) * ldb + ldK;
    const size_t rstepA = (size_t)64 * lda;
    const size_t rstepB = (size_t)64 * ldb;

    const int wbyte = (tid & ~63) * 16;
    char* dA = (char*)sA + wbyte;
    char* dB = (char*)sB + wbyte;

    f32x4 acc[4][4];
#pragma unroll
    for (int i = 0; i < 4; i++)
#pragma unroll
        for (int j = 0; j < 4; j++) acc[i][j] = {0.f, 0.f, 0.f, 0.f};

    const int fr = lane & 15;
    const int q8 = (lane >> 4) * 8;

    for (int kt = 0; kt < KT; ++kt) {
        const int k0 = kt * 32;
        __syncthreads();
        gl_lds16(aP + k0, dA);
        gl_lds16(aP + k0 + rstepA, dA + 4096);
        gl_lds16(bP + k0, dB);
        gl_lds16(bP + k0 + rstepB, dB + 4096);
        __syncthreads();

        half8 bh[4];
#pragma unroll
        for (int j = 0; j < 4; j++) {
            int brow = wc * 64 + j * 16 + fr;
            bh[j] = *(const half8*)&sB[brow * 32 + q8];
        }
#pragma unroll
        for (int i = 0; i < 4; i++) {
            int arow = wr * 64 + i * 16 + fr;
            half8 ah = *(const half8*)&sA[arow * 32 + q8];
#pragma unroll
            for (int j = 0; j < 4; j++)
                acc[i][j] = __builtin_amdgcn_mfma_f32_16x16x32_f16(ah, bh[j], acc[i][j], 0, 0, 0);
        }
    }

    const int lr = (lane >> 4) * 4;
    const int lc = lane & 15;
#pragma unroll
    for (int j = 0; j < 4; j++) {
        const int col = n0 + wc * 64 + j * 16 + lc;
        const float bj = bias[col];
#pragma unroll
        for (int i = 0; i < 4; i++) {
            const int rb = m0 + wr * 64 + i * 16 + lr;
#pragma unroll
            for (int r = 0; r < 4; r++)
                C[(size_t)(rb + r) * ldc + col] = (f16)(acc[i][j][r] + bj);
        }
    }
}

// ---------- per-dst aggregation (pull via CSR, no atomics) -> ah cols 0..255 ----------
__global__ __launch_bounds__(256) void k_agg(const f16* __restrict__ Wh,
                                             const int* __restrict__ rowptr,
                                             const int* __restrict__ colpk,
                                             f16* __restrict__ ah) {
    int n = blockIdx.x, c = threadIdx.x;
    float s = 0.f;
    if (n < NN) {
        int e0 = rowptr[n], e1 = rowptr[n + 1];
        for (int e = e0; e < e1; ++e) {
            int pk = colpk[e];
            int sr = pk & 0xFFFF;
            int t = pk >> 16;
            s += (float)Wh[(size_t)sr * 1024 + t * 256 + c];
        }
    }
    ah[(size_t)n * 512 + c] = (f16)s;
}

// ---------- GRU cell elementwise: G = [rsum(256)|zsum(256)|i_n(256)|h_n(256)] ----------
__global__ __launch_bounds__(256) void k_gru(const float* __restrict__ G,
                                             f16* __restrict__ ah) {
    int n = blockIdx.x, c = threadIdx.x;
    size_t b = (size_t)n * 1024 + c;
    float rsum = G[b], zsum = G[b + 256], inn = G[b + 512], hn = G[b + 768];
    float r = 1.f / (1.f + expf(-rsum));
    float z = 1.f / (1.f + expf(-zsum));
    float nn = tanhf(inn + r * hn);
    size_t i = (size_t)n * 512 + 256 + c;
    float hv = (float)ah[i];
    float o = (1.f - z) * nn + z * hv;
    ah[i] = (f16)o;
}

// ---------- tail: elu + BN stats (h2 = raw elu output, f32) ----------
__global__ __launch_bounds__(256) void k_elu_stats(const f16* __restrict__ ah,
                                                   float* __restrict__ h2,
                                                   float* __restrict__ bnsum,
                                                   float* __restrict__ bnsq) {
    int c = threadIdx.x;
    int r0 = blockIdx.x * 128;
    int r1 = min(r0 + 128, NN);
    float s = 0.f, q = 0.f;
    for (int n = r0; n < r1; ++n) {
        float x = (float)ah[(size_t)n * 512 + 256 + c];
        float e = x > 0.f ? x : expm1f(x);
        h2[(size_t)n * HH + c] = e;
        s += e;
        q += e * e;
    }
    atomicAdd(&bnsum[c], s);
    atomicAdd(&bnsq[c], q);
}

// ---------- fold BN affine into gate weights: wp[0..255], wp[256]=const ----------
__global__ __launch_bounds__(256) void k_prep(const float* __restrict__ bnsum,
                                              const float* __restrict__ bnsq,
                                              const float* __restrict__ gamma,
                                              const float* __restrict__ beta,
                                              const float* __restrict__ gate_w,
                                              const float* __restrict__ gate_b,
                                              float* __restrict__ wp) {
    __shared__ float red[256];
    int c = threadIdx.x;
    float mu = bnsum[c] * (1.f / NN);
    float var = bnsq[c] * (1.f / NN) - mu * mu;
    float rs = rsqrtf(var + 1e-5f);
    float gm = gamma[c], w = gate_w[c];
    wp[c] = rs * gm * w;
    red[c] = (beta[c] - mu * rs * gm) * w;
    __syncthreads();
    for (int st = 128; st > 0; st >>= 1) {
        if (c < st) red[c] += red[c + st];
        __syncthreads();
    }
    if (c == 0) wp[256] = red[0] + gate_b[0];
}

// ---------- gate score: wave dots, LDS-staged segment max (few global atomics) ----------
__global__ __launch_bounds__(256) void k_gate(const float* __restrict__ h2,
                                              const float* __restrict__ wp,
                                              const int* __restrict__ n2g,
                                              float* __restrict__ gate,
                                              u32* __restrict__ gmaxenc) {
    __shared__ u32 smax[64];
    int tid = threadIdx.x;
    if (tid < 64) smax[tid] = 0;
    __syncthreads();
    int lane = tid & 63, wv = tid >> 6;
    int base = blockIdx.x * 128 + wv * 32;       // each wave: 32 consecutive nodes
    float4 w = ((const float4*)wp)[lane];
    float wc = wp[256];
    for (int k = 0; k < 32; ++k) {
        int n = base + k;
        if (n >= NN) break;
        float4 v = ((const float4*)(h2 + (size_t)n * HH))[lane];
        float s = v.x * w.x + v.y * w.y + v.z * w.z + v.w * w.w;
#pragma unroll
        for (int off = 32; off; off >>= 1) s += __shfl_down(s, off);
        if (lane == 0) {
            float gt = s + wc;
            gate[n] = gt;
            atomicMax(&smax[n2g[n]], encf(gt));
        }
    }
    __syncthreads();
    if (tid < 64 && smax[tid]) atomicMax(&gmaxenc[tid], smax[tid]);
}

// ---------- exp + denom (LDS-staged segment sum) ----------
__global__ __launch_bounds__(256) void k_expden(float* __restrict__ gate,
                                                const int* __restrict__ n2g,
                                                const u32* __restrict__ gmaxenc,
                                                float* __restrict__ denom) {
    __shared__ float ssum[64];
    int tid = threadIdx.x;
    if (tid < 64) ssum[tid] = 0.f;
    __syncthreads();
    int n = blockIdx.x * 256 + tid;
    if (n < NN) {
        int g = n2g[n];
        float e = expf(gate[n] - decf(gmaxenc[g]));
        gate[n] = e;
        atomicAdd(&ssum[g], e);
    }
    __syncthreads();
    if (tid < 64 && ssum[tid] != 0.f) atomicAdd(&denom[tid], ssum[tid]);
}

// ---------- attention pooling over RAW h2 (n2g sorted; flush on graph change) ----------
__global__ __launch_bounds__(256) void k_pool(const float* __restrict__ h2,
                                              const float* __restrict__ gate,
                                              const float* __restrict__ denom,
                                              const int* __restrict__ n2g,
                                              float* __restrict__ h_g) {
    int c = threadIdx.x;
    int r0 = blockIdx.x * 128, r1 = min(r0 + 128, NN);
    int gcur = -1;
    float accv = 0.f, inv = 0.f;
    for (int n = r0; n < r1; ++n) {
        int g = n2g[n];
        if (g != gcur) {
            if (gcur >= 0) atomicAdd(&h_g[gcur * HH + c], accv);
            gcur = g;
            accv = 0.f;
            inv = 1.f / denom[g];
        }
        accv += gate[n] * inv * h2[(size_t)n * HH + c];
    }
    if (gcur >= 0) atomicAdd(&h_g[gcur * HH + c], accv);
}

// ---------- classifier (applies BN affine to pooled vector) ----------
__global__ __launch_bounds__(256) void k_cls(const float* __restrict__ h_g,
                                             const float* __restrict__ bnsum,
                                             const float* __restrict__ bnsq,
                                             const float* __restrict__ gamma,
                                             const float* __restrict__ beta,
                                             const float* __restrict__ W1,
                                             const float* __restrict__ b1,
                                             const float* __restrict__ W2,
                                             const float* __restrict__ b2,
                                             float* __restrict__ out) {
    __shared__ float hg[256];
    __shared__ float x1[128];
    int g = blockIdx.x, tid = threadIdx.x;
    float mu = bnsum[tid] * (1.f / NN);
    float var = bnsq[tid] * (1.f / NN) - mu * mu;
    hg[tid] = (h_g[g * HH + tid] - mu) * rsqrtf(var + 1e-5f) * gamma[tid] + beta[tid];
    __syncthreads();
    if (tid < 128) {
        const float* w = W1 + tid * 256;
        float s = b1[tid];
#pragma unroll 8
        for (int c = 0; c < 256; ++c) s += hg[c] * w[c];
        x1[tid] = fmaxf(s, 0.f);
    }
    __syncthreads();
    if (tid < 10) {
        const float* w = W2 + tid * 128;
        float s = b2[tid];
        for (int j = 0; j < 128; ++j) s += x1[j] * w[j];
        out[g * CC + tid] = s;
    }
}

// =======================================================================
extern "C" void kernel_launch(void* const* d_in, const int* in_sizes, int n_in,
                              void* d_out, int out_size, void* d_ws, size_t ws_size,
                              hipStream_t stream) {
    const float* feat  = (const float*)d_in[0];
    const int*   src   = (const int*)d_in[1];
    const int*   dst   = (const int*)d_in[2];
    const int*   etype = (const int*)d_in[3];
    const int*   n2g   = (const int*)d_in[4];
    const float* W_msg = (const float*)d_in[5];
    const float* b_msg = (const float*)d_in[6];
    const float* w_ih  = (const float*)d_in[7];
    const float* w_hh  = (const float*)d_in[8];
    const float* b_ih  = (const float*)d_in[9];
    const float* b_hh  = (const float*)d_in[10];
    const float* bn_g  = (const float*)d_in[11];
    const float* bn_b  = (const float*)d_in[12];
    const float* gatew = (const float*)d_in[13];
    const float* gateb = (const float*)d_in[14];
    const float* W1    = (const float*)d_in[15];
    const float* b1    = (const float*)d_in[16];
    const float* W2    = (const float*)d_in[17];
    const float* b2    = (const float*)d_in[18];
    float* out = (float*)d_out;

    char* ws = (char*)d_ws;
    size_t off = 0;
    auto alloc = [&](size_t bytes) -> char* {
        char* p = ws + off;
        off += (bytes + 255) & ~(size_t)255;
        return p;
    };

    // zero zone (single memset): cnt | bnsum | bnsq | denom | gmaxenc | h_g
    const size_t ZZ = (size_t)(NN + 256 + 256 + 64 + 64 + GG * HH) * 4;
    char* zz = alloc(ZZ);
    int*   cnt     = (int*)zz;
    float* bnsum   = (float*)(zz + (size_t)NN * 4);
    float* bnsq    = bnsum + 256;
    float* denom   = bnsq + 256;
    u32*   gmaxenc = (u32*)(denom + 64);
    float* h_g     = (float*)(gmaxenc + 64);

    int* rowptr = (int*)alloc((NN + 1) * 4);
    int* cur    = (int*)alloc(NN * 4);
    int* colpk  = (int*)alloc((size_t)EE * 4);
    float* gate = (float*)alloc(NN * 4);
    float* wp   = (float*)alloc(260 * 4);

    // interleaved node state: cols 0..255 = a, cols 256..511 = h (fp16)
    f16* ah = (f16*)alloc((size_t)MP * 512 * 2);

    f16* wmsg = (f16*)alloc((size_t)1024 * 256 * 2);
    f16* wrz  = (f16*)alloc((size_t)512 * 512 * 2);
    f16* win  = (f16*)alloc((size_t)256 * 256 * 2);
    f16* whn  = (f16*)alloc((size_t)256 * 256 * 2);
    float* brz = (float*)alloc(512 * 4);

    // big region: G f32 [MP x 1024]; Wh fp16 [MP x 1024] and h2 f32 [MP x 256] overlap it
    char* big = alloc((size_t)MP * 1024 * 4);
    float* G  = (float*)big;
    f16*   Wh = (f16*)big;
    float* h2 = (float*)big;

    hipMemsetAsync(zz, 0, ZZ, stream);

    k_convert<<<1024, 256, 0, stream>>>(W_msg, wmsg, 1024 * 256);
    k_convert<<<256, 256, 0, stream>>>(w_ih + 512 * 256, win, 256 * 256);
    k_convert<<<256, 256, 0, stream>>>(w_hh + 512 * 256, whn, 256 * 256);
    k_pack_rz<<<1024, 256, 0, stream>>>(w_ih, w_hh, wrz);
    k_brz<<<2, 256, 0, stream>>>(b_ih, b_hh, brz);
    k_feat<<<MP, 256, 0, stream>>>(feat, ah);

    k_count<<<(EE + 255) / 256, 256, 0, stream>>>(dst, cnt);
    k_scan<<<1, 1024, 0, stream>>>(cnt, rowptr, cur);
    k_fill<<<(EE + 255) / 256, 256, 0, stream>>>(src, dst, etype, cur, colpk);

    for (int s = 0; s < 5; ++s) {
        // Wh = h * W_msg^T  [MP x 1024] fp16
        gemm_f16_o16<<<dim3(8, MP / 128), 256, 0, stream>>>(
            ah + 256, 512, wmsg, 256, b_msg, Wh, 1024, 8);
        k_agg<<<MP, 256, 0, stream>>>(Wh, rowptr, colpk, ah);
        // rsum|zsum = [a|h] * wrz^T (K=512) -> G cols 0..511
        gemm_f16<<<dim3(4, MP / 128), 256, 0, stream>>>(
            ah, 512, wrz, 512, brz, G, 1024, 16);
        // i_n = a * w_in^T (K=256) -> G cols 512..767
        gemm_f16<<<dim3(2, MP / 128), 256, 0, stream>>>(
            ah, 512, win, 256, b_ih + 512, G + 512, 1024, 8);
        // h_n = h * w_hn^T (K=256) -> G cols 768..1023
        gemm_f16<<<dim3(2, MP / 128), 256, 0, stream>>>(
            ah + 256, 512, whn, 256, b_hh + 512, G + 768, 1024, 8);
        k_gru<<<MP, 256, 0, stream>>>(G, ah);
    }

    k_elu_stats<<<235, 256, 0, stream>>>(ah, h2, bnsum, bnsq);
    k_prep<<<1, 256, 0, stream>>>(bnsum, bnsq, bn_g, bn_b, gatew, gateb, wp);
    k_gate<<<235, 256, 0, stream>>>(h2, wp, n2g, gate, gmaxenc);
    k_expden<<<(NN + 255) / 256, 256, 0, stream>>>(gate, n2g, gmaxenc, denom);
    k_pool<<<235, 256, 0, stream>>>(h2, gate, denom, n2g, h_g);
    k_cls<<<GG, 256, 0, stream>>>(h_g, bnsum, bnsq, bn_g, bn_b, W1, b1, W2, b2, out);

    (void)in_sizes; (void)n_in; (void)out_size; (void)ws_size;
}

// Round 6
// 1157.275 us; speedup vs baseline: 1.9255x; 1.2577x over previous
//
#include <hip/hip_runtime.h>

#define NN 30000
#define EE 480000
#define HH 256
#define TT 4
#define GG 64
#define CC 10
#define MP 30080   // 235 * 128, padded rows

typedef unsigned short u16;
typedef unsigned int u32;
typedef _Float16 f16;
typedef f16 half8 __attribute__((ext_vector_type(8)));
typedef f16 half4 __attribute__((ext_vector_type(4)));
typedef float f32x4 __attribute__((ext_vector_type(4)));

// ---------- helpers ----------
__device__ __forceinline__ u32 encf(float x) {       // order-preserving float->uint
    u32 u = __float_as_uint(x);
    return (u & 0x80000000u) ? ~u : (u | 0x80000000u);
}
__device__ __forceinline__ float decf(u32 e) {
    u32 u = (e & 0x80000000u) ? (e ^ 0x80000000u) : ~e;
    return __uint_as_float(u);
}
__device__ __forceinline__ void gl_lds16(const void* g, void* l) {
    __builtin_amdgcn_global_load_lds(
        (const __attribute__((address_space(1))) void*)g,
        (__attribute__((address_space(3))) void*)l, 16, 0, 0);
}

// ---------- conversion / packing kernels ----------
__global__ void k_convert(const float* __restrict__ in, f16* __restrict__ o, int n) {
    int i = blockIdx.x * 256 + threadIdx.x;
    if (i < n) o[i] = (f16)in[i];
}

// wrz[j][k] = k<256 ? w_ih[j][k] : w_hh[j][k-256]   (j<512: r,z rows)
__global__ void k_pack_rz(const float* __restrict__ w_ih, const float* __restrict__ w_hh,
                          f16* __restrict__ o) {
    int i = blockIdx.x * 256 + threadIdx.x;   // over 512*512
    int j = i >> 9, k = i & 511;
    o[i] = (f16)((k < 256) ? w_ih[j * 256 + k] : w_hh[j * 256 + (k - 256)]);
}

__global__ void k_brz(const float* __restrict__ b_ih, const float* __restrict__ b_hh,
                      float* __restrict__ brz) {
    int j = threadIdx.x + blockIdx.x * 256;
    if (j < 512) brz[j] = b_ih[j] + b_hh[j];
}

// h state -> ah cols 256..511. Padded rows = 0.
__global__ __launch_bounds__(256) void k_feat(const float* __restrict__ feat,
                                              f16* __restrict__ ah) {
    int n = blockIdx.x, c = threadIdx.x;
    float v = (n < NN) ? feat[(size_t)n * HH + c] : 0.f;
    ah[(size_t)n * 512 + 256 + c] = (f16)v;
}

// ---------- CSR build ----------
__global__ void k_count(const int* __restrict__ dst, int* __restrict__ cnt) {
    int e = blockIdx.x * 256 + threadIdx.x;
    if (e < EE) atomicAdd(&cnt[dst[e]], 1);
}

__global__ __launch_bounds__(1024) void k_scan(const int* __restrict__ cnt,
                                               int* __restrict__ rowptr,
                                               int* __restrict__ cur) {
    __shared__ int buf[1024];
    __shared__ int carry;
    int tid = threadIdx.x;
    if (tid == 0) carry = 0;
    __syncthreads();
    for (int base = 0; base < NN; base += 1024) {
        int x = (base + tid < NN) ? cnt[base + tid] : 0;
        buf[tid] = x;
        __syncthreads();
        for (int ofs = 1; ofs < 1024; ofs <<= 1) {
            int v = (tid >= ofs) ? buf[tid - ofs] : 0;
            __syncthreads();
            buf[tid] += v;
            __syncthreads();
        }
        int excl = buf[tid] - x + carry;
        if (base + tid < NN) { rowptr[base + tid] = excl; cur[base + tid] = excl; }
        int total = buf[1023];
        __syncthreads();
        if (tid == 0) carry += total;
        __syncthreads();
    }
    if (tid == 0) rowptr[NN] = EE;
}

__global__ void k_fill(const int* __restrict__ src, const int* __restrict__ dst,
                       const int* __restrict__ et, int* __restrict__ cur,
                       int* __restrict__ colpk) {
    int e = blockIdx.x * 256 + threadIdx.x;
    if (e < EE) {
        int pos = atomicAdd(&cur[dst[e]], 1);
        colpk[pos] = (et[e] << 16) | src[e];
    }
}

// ---------- fp16 MFMA GEMM: C[128y x 128x] = A[. x K] * B[. x K]^T + bias ----------
__global__ __launch_bounds__(256) void gemm_f16(
    const f16* __restrict__ A, int lda,
    const f16* __restrict__ B, int ldb,
    const float* __restrict__ bias, float* __restrict__ C, int ldc, int KT) {
    __shared__ f16 sA[4096], sB[4096];           // 128 rows x 32 k
    const int tid = threadIdx.x;
    const int lane = tid & 63;
    const int wv = tid >> 6;
    const int wr = wv >> 1, wc = wv & 1;
    const int m0 = blockIdx.y * 128, n0 = blockIdx.x * 128;

    const int ldRow = tid >> 2;
    const int ldK = (tid & 3) * 8;
    const f16* aP = A + (size_t)(m0 + ldRow) * lda + ldK;
    const f16* bP = B + (size_t)(n0 + ldRow) * ldb + ldK;
    const size_t rstepA = (size_t)64 * lda;
    const size_t rstepB = (size_t)64 * ldb;

    const int wbyte = (tid & ~63) * 16;   // wave-uniform LDS base (lane0 of wave)
    char* dA = (char*)sA + wbyte;
    char* dB = (char*)sB + wbyte;

    f32x4 acc[4][4];
#pragma unroll
    for (int i = 0; i < 4; i++)
#pragma unroll
        for (int j = 0; j < 4; j++) acc[i][j] = {0.f, 0.f, 0.f, 0.f};

    const int fr = lane & 15;
    const int q8 = (lane >> 4) * 8;

    for (int kt = 0; kt < KT; ++kt) {
        const int k0 = kt * 32;
        __syncthreads();
        gl_lds16(aP + k0, dA);
        gl_lds16(aP + k0 + rstepA, dA + 4096);
        gl_lds16(bP + k0, dB);
        gl_lds16(bP + k0 + rstepB, dB + 4096);
        __syncthreads();

        half8 bh[4];
#pragma unroll
        for (int j = 0; j < 4; j++) {
            int brow = wc * 64 + j * 16 + fr;
            bh[j] = *(const half8*)&sB[brow * 32 + q8];
        }
#pragma unroll
        for (int i = 0; i < 4; i++) {
            int arow = wr * 64 + i * 16 + fr;
            half8 ah = *(const half8*)&sA[arow * 32 + q8];
#pragma unroll
            for (int j = 0; j < 4; j++)
                acc[i][j] = __builtin_amdgcn_mfma_f32_16x16x32_f16(ah, bh[j], acc[i][j], 0, 0, 0);
        }
    }

    // C/D layout (verified m89/m91): col = lane&15, row = (lane>>4)*4 + reg
    const int lr = (lane >> 4) * 4;
    const int lc = lane & 15;
#pragma unroll
    for (int j = 0; j < 4; j++) {
        const int col = n0 + wc * 64 + j * 16 + lc;
        const float bj = bias[col];
#pragma unroll
        for (int i = 0; i < 4; i++) {
            const int rb = m0 + wr * 64 + i * 16 + lr;
#pragma unroll
            for (int r = 0; r < 4; r++)
                C[(size_t)(rb + r) * ldc + col] = acc[i][j][r] + bj;
        }
    }
}

// same GEMM but fp16 output (for Wh)
__global__ __launch_bounds__(256) void gemm_f16_o16(
    const f16* __restrict__ A, int lda,
    const f16* __restrict__ B, int ldb,
    const float* __restrict__ bias, f16* __restrict__ C, int ldc, int KT) {
    __shared__ f16 sA[4096], sB[4096];
    const int tid = threadIdx.x;
    const int lane = tid & 63;
    const int wv = tid >> 6;
    const int wr = wv >> 1, wc = wv & 1;
    const int m0 = blockIdx.y * 128, n0 = blockIdx.x * 128;

    const int ldRow = tid >> 2;
    const int ldK = (tid & 3) * 8;
    const f16* aP = A + (size_t)(m0 + ldRow) * lda + ldK;
    const f16* bP = B + (size_t)(n0 + ldRow) * ldb + ldK;
    const size_t rstepA = (size_t)64 * lda;
    const size_t rstepB = (size_t)64 * ldb;

    const int wbyte = (tid & ~63) * 16;
    char* dA = (char*)sA + wbyte;
    char* dB = (char*)sB + wbyte;

    f32x4 acc[4][4];
#pragma unroll
    for (int i = 0; i < 4; i++)
#pragma unroll
        for (int j = 0; j < 4; j++) acc[i][j] = {0.f, 0.f, 0.f, 0.f};

    const int fr = lane & 15;
    const int q8 = (lane >> 4) * 8;

    for (int kt = 0; kt < KT; ++kt) {
        const int k0 = kt * 32;
        __syncthreads();
        gl_lds16(aP + k0, dA);
        gl_lds16(aP + k0 + rstepA, dA + 4096);
        gl_lds16(bP + k0, dB);
        gl_lds16(bP + k0 + rstepB, dB + 4096);
        __syncthreads();

        half8 bh[4];
#pragma unroll
        for (int j = 0; j < 4; j++) {
            int brow = wc * 64 + j * 16 + fr;
            bh[j] = *(const half8*)&sB[brow * 32 + q8];
        }
#pragma unroll
        for (int i = 0; i < 4; i++) {
            int arow = wr * 64 + i * 16 + fr;
            half8 ah = *(const half8*)&sA[arow * 32 + q8];
#pragma unroll
            for (int j = 0; j < 4; j++)
                acc[i][j] = __builtin_amdgcn_mfma_f32_16x16x32_f16(ah, bh[j], acc[i][j], 0, 0, 0);
        }
    }

    const int lr = (lane >> 4) * 4;
    const int lc = lane & 15;
#pragma unroll
    for (int j = 0; j < 4; j++) {
        const int col = n0 + wc * 64 + j * 16 + lc;
        const float bj = bias[col];
#pragma unroll
        for (int i = 0; i < 4; i++) {
            const int rb = m0 + wr * 64 + i * 16 + lr;
#pragma unroll
            for (int r = 0; r < 4; r++)
                C[(size_t)(rb + r) * ldc + col] = (f16)(acc[i][j][r] + bj);
        }
    }
}

// ---------- per-dst aggregation (pull via CSR, latency-hidden) -> ah cols 0..255 ----------
// 64 lanes x 4 edge-strips; each lane covers 4 cols via f16x4 loads; colpk staged in LDS.
__global__ __launch_bounds__(256) void k_agg(const f16* __restrict__ Wh,
                                             const int* __restrict__ rowptr,
                                             const int* __restrict__ colpk,
                                             f16* __restrict__ ah) {
    __shared__ int spk[256];
    __shared__ float4 sacc[3][64];
    const int n = blockIdx.x;
    const int tid = threadIdx.x;
    const int col4 = tid & 63;         // cols 4*col4 .. 4*col4+3
    const int strip = tid >> 6;        // 0..3 (== wave id)
    float4 acc = {0.f, 0.f, 0.f, 0.f};

    if (n < NN) {
        const int e0 = rowptr[n], e1 = rowptr[n + 1];
        for (int base = e0; base < e1; base += 256) {
            const int chunk = min(256, e1 - base);
            __syncthreads();
            if (tid < chunk) spk[tid] = colpk[base + tid];
            __syncthreads();
            int i = strip;
            // 2x unroll: 2 independent loads in flight per thread (8 edges/block)
            for (; i + 4 < chunk; i += 8) {
                const int pk0 = spk[i], pk1 = spk[i + 4];
                const half4 v0 = *(const half4*)&Wh[(size_t)(pk0 & 0xFFFF) * 1024 + (pk0 >> 16) * 256 + col4 * 4];
                const half4 v1 = *(const half4*)&Wh[(size_t)(pk1 & 0xFFFF) * 1024 + (pk1 >> 16) * 256 + col4 * 4];
                acc.x += (float)v0.x + (float)v1.x;
                acc.y += (float)v0.y + (float)v1.y;
                acc.z += (float)v0.z + (float)v1.z;
                acc.w += (float)v0.w + (float)v1.w;
            }
            for (; i < chunk; i += 4) {
                const int pk = spk[i];
                const half4 v = *(const half4*)&Wh[(size_t)(pk & 0xFFFF) * 1024 + (pk >> 16) * 256 + col4 * 4];
                acc.x += (float)v.x;
                acc.y += (float)v.y;
                acc.z += (float)v.z;
                acc.w += (float)v.w;
            }
        }
    }
    if (strip) sacc[strip - 1][col4] = acc;
    __syncthreads();
    if (strip == 0 && n < NN) {
        const float4 t0 = sacc[0][col4], t1 = sacc[1][col4], t2 = sacc[2][col4];
        half4 o;
        o.x = (f16)(acc.x + t0.x + t1.x + t2.x);
        o.y = (f16)(acc.y + t0.y + t1.y + t2.y);
        o.z = (f16)(acc.z + t0.z + t1.z + t2.z);
        o.w = (f16)(acc.w + t0.w + t1.w + t2.w);
        *(half4*)&ah[(size_t)n * 512 + col4 * 4] = o;
    }
}

// ---------- GRU cell elementwise: G = [rsum(256)|zsum(256)|i_n(256)|h_n(256)] ----------
__global__ __launch_bounds__(256) void k_gru(const float* __restrict__ G,
                                             f16* __restrict__ ah) {
    int n = blockIdx.x, c = threadIdx.x;
    size_t b = (size_t)n * 1024 + c;
    float rsum = G[b], zsum = G[b + 256], inn = G[b + 512], hn = G[b + 768];
    float r = 1.f / (1.f + expf(-rsum));
    float z = 1.f / (1.f + expf(-zsum));
    float nn = tanhf(inn + r * hn);
    size_t i = (size_t)n * 512 + 256 + c;
    float hv = (float)ah[i];
    float o = (1.f - z) * nn + z * hv;
    ah[i] = (f16)o;
}

// ---------- tail: elu + BN stats (h2 = raw elu output, f32) ----------
__global__ __launch_bounds__(256) void k_elu_stats(const f16* __restrict__ ah,
                                                   float* __restrict__ h2,
                                                   float* __restrict__ bnsum,
                                                   float* __restrict__ bnsq) {
    int c = threadIdx.x;
    int r0 = blockIdx.x * 128;
    int r1 = min(r0 + 128, NN);
    float s = 0.f, q = 0.f;
    for (int n = r0; n < r1; ++n) {
        float x = (float)ah[(size_t)n * 512 + 256 + c];
        float e = x > 0.f ? x : expm1f(x);
        h2[(size_t)n * HH + c] = e;
        s += e;
        q += e * e;
    }
    atomicAdd(&bnsum[c], s);
    atomicAdd(&bnsq[c], q);
}

// ---------- fold BN affine into gate weights: wp[0..255], wp[256]=const ----------
__global__ __launch_bounds__(256) void k_prep(const float* __restrict__ bnsum,
                                              const float* __restrict__ bnsq,
                                              const float* __restrict__ gamma,
                                              const float* __restrict__ beta,
                                              const float* __restrict__ gate_w,
                                              const float* __restrict__ gate_b,
                                              float* __restrict__ wp) {
    __shared__ float red[256];
    int c = threadIdx.x;
    float mu = bnsum[c] * (1.f / NN);
    float var = bnsq[c] * (1.f / NN) - mu * mu;
    float rs = rsqrtf(var + 1e-5f);
    float gm = gamma[c], w = gate_w[c];
    wp[c] = rs * gm * w;
    red[c] = (beta[c] - mu * rs * gm) * w;
    __syncthreads();
    for (int st = 128; st > 0; st >>= 1) {
        if (c < st) red[c] += red[c + st];
        __syncthreads();
    }
    if (c == 0) wp[256] = red[0] + gate_b[0];
}

// ---------- gate score: wave dots, LDS-staged segment max (few global atomics) ----------
__global__ __launch_bounds__(256) void k_gate(const float* __restrict__ h2,
                                              const float* __restrict__ wp,
                                              const int* __restrict__ n2g,
                                              float* __restrict__ gate,
                                              u32* __restrict__ gmaxenc) {
    __shared__ u32 smax[64];
    int tid = threadIdx.x;
    if (tid < 64) smax[tid] = 0;
    __syncthreads();
    int lane = tid & 63, wv = tid >> 6;
    int base = blockIdx.x * 128 + wv * 32;       // each wave: 32 consecutive nodes
    float4 w = ((const float4*)wp)[lane];
    float wc = wp[256];
    for (int k = 0; k < 32; ++k) {
        int n = base + k;
        if (n >= NN) break;
        float4 v = ((const float4*)(h2 + (size_t)n * HH))[lane];
        float s = v.x * w.x + v.y * w.y + v.z * w.z + v.w * w.w;
#pragma unroll
        for (int off = 32; off; off >>= 1) s += __shfl_down(s, off);
        if (lane == 0) {
            float gt = s + wc;
            gate[n] = gt;
            atomicMax(&smax[n2g[n]], encf(gt));
        }
    }
    __syncthreads();
    if (tid < 64 && smax[tid]) atomicMax(&gmaxenc[tid], smax[tid]);
}

// ---------- exp + denom (LDS-staged segment sum) ----------
__global__ void k_expden(float* __restrict__ gate,
                         const int* __restrict__ n2g,
                         const u32* __restrict__ gmaxenc,
                         float* __restrict__ denom) {
    __shared__ float ssum[64];
    int tid = threadIdx.x;
    if (tid < 64) ssum[tid] = 0.f;
    __syncthreads();
    int n = blockIdx.x * 256 + tid;
    if (n < NN) {
        int g = n2g[n];
        float e = expf(gate[n] - decf(gmaxenc[g]));
        gate[n] = e;
        atomicAdd(&ssum[g], e);
    }
    __syncthreads();
    if (tid < 64 && ssum[tid] != 0.f) atomicAdd(&denom[tid], ssum[tid]);
}

// ---------- attention pooling over RAW h2 (n2g sorted; flush on graph change) ----------
__global__ __launch_bounds__(256) void k_pool(const float* __restrict__ h2,
                                              const float* __restrict__ gate,
                                              const float* __restrict__ denom,
                                              const int* __restrict__ n2g,
                                              float* __restrict__ h_g) {
    int c = threadIdx.x;
    int r0 = blockIdx.x * 128, r1 = min(r0 + 128, NN);
    int gcur = -1;
    float accv = 0.f, inv = 0.f;
    for (int n = r0; n < r1; ++n) {
        int g = n2g[n];
        if (g != gcur) {
            if (gcur >= 0) atomicAdd(&h_g[gcur * HH + c], accv);
            gcur = g;
            accv = 0.f;
            inv = 1.f / denom[g];
        }
        accv += gate[n] * inv * h2[(size_t)n * HH + c];
    }
    if (gcur >= 0) atomicAdd(&h_g[gcur * HH + c], accv);
}

// ---------- classifier (applies BN affine to pooled vector) ----------
__global__ __launch_bounds__(256) void k_cls(const float* __restrict__ h_g,
                                             const float* __restrict__ bnsum,
                                             const float* __restrict__ bnsq,
                                             const float* __restrict__ gamma,
                                             const float* __restrict__ beta,
                                             const float* __restrict__ W1,
                                             const float* __restrict__ b1,
                                             const float* __restrict__ W2,
                                             const float* __restrict__ b2,
                                             float* __restrict__ out) {
    __shared__ float hg[256];
    __shared__ float x1[128];
    int g = blockIdx.x, tid = threadIdx.x;
    float mu = bnsum[tid] * (1.f / NN);
    float var = bnsq[tid] * (1.f / NN) - mu * mu;
    hg[tid] = (h_g[g * HH + tid] - mu) * rsqrtf(var + 1e-5f) * gamma[tid] + beta[tid];
    __syncthreads();
    if (tid < 128) {
        const float* w = W1 + tid * 256;
        float s = b1[tid];
#pragma unroll 8
        for (int c = 0; c < 256; ++c) s += hg[c] * w[c];
        x1[tid] = fmaxf(s, 0.f);
    }
    __syncthreads();
    if (tid < 10) {
        const float* w = W2 + tid * 128;
        float s = b2[tid];
        for (int j = 0; j < 128; ++j) s += x1[j] * w[j];
        out[g * CC + tid] = s;
    }
}

// =======================================================================
extern "C" void kernel_launch(void* const* d_in, const int* in_sizes, int n_in,
                              void* d_out, int out_size, void* d_ws, size_t ws_size,
                              hipStream_t stream) {
    const float* feat  = (const float*)d_in[0];
    const int*   src   = (const int*)d_in[1];
    const int*   dst   = (const int*)d_in[2];
    const int*   etype = (const int*)d_in[3];
    const int*   n2g   = (const int*)d_in[4];
    const float* W_msg = (const float*)d_in[5];
    const float* b_msg = (const float*)d_in[6];
    const float* w_ih  = (const float*)d_in[7];
    const float* w_hh  = (const float*)d_in[8];
    const float* b_ih  = (const float*)d_in[9];
    const float* b_hh  = (const float*)d_in[10];
    const float* bn_g  = (const float*)d_in[11];
    const float* bn_b  = (const float*)d_in[12];
    const float* gatew = (const float*)d_in[13];
    const float* gateb = (const float*)d_in[14];
    const float* W1    = (const float*)d_in[15];
    const float* b1    = (const float*)d_in[16];
    const float* W2    = (const float*)d_in[17];
    const float* b2    = (const float*)d_in[18];
    float* out = (float*)d_out;

    char* ws = (char*)d_ws;
    size_t off = 0;
    auto alloc = [&](size_t bytes) -> char* {
        char* p = ws + off;
        off += (bytes + 255) & ~(size_t)255;
        return p;
    };

    // zero zone (single memset): cnt | bnsum | bnsq | denom | gmaxenc | h_g
    const size_t ZZ = (size_t)(NN + 256 + 256 + 64 + 64 + GG * HH) * 4;
    char* zz = alloc(ZZ);
    int*   cnt     = (int*)zz;
    float* bnsum   = (float*)(zz + (size_t)NN * 4);
    float* bnsq    = bnsum + 256;
    float* denom   = bnsq + 256;
    u32*   gmaxenc = (u32*)(denom + 64);
    float* h_g     = (float*)(gmaxenc + 64);

    int* rowptr = (int*)alloc((NN + 1) * 4);
    int* cur    = (int*)alloc(NN * 4);
    int* colpk  = (int*)alloc((size_t)EE * 4);
    float* gate = (float*)alloc(NN * 4);
    float* wp   = (float*)alloc(260 * 4);

    // interleaved node state: cols 0..255 = a, cols 256..511 = h (fp16)
    f16* ah = (f16*)alloc((size_t)MP * 512 * 2);

    f16* wmsg = (f16*)alloc((size_t)1024 * 256 * 2);
    f16* wrz  = (f16*)alloc((size_t)512 * 512 * 2);
    f16* win  = (f16*)alloc((size_t)256 * 256 * 2);
    f16* whn  = (f16*)alloc((size_t)256 * 256 * 2);
    float* brz = (float*)alloc(512 * 4);

    // big region: G f32 [MP x 1024]; Wh fp16 [MP x 1024] and h2 f32 [MP x 256] overlap it
    char* big = alloc((size_t)MP * 1024 * 4);
    float* G  = (float*)big;
    f16*   Wh = (f16*)big;
    float* h2 = (float*)big;

    hipMemsetAsync(zz, 0, ZZ, stream);

    k_convert<<<1024, 256, 0, stream>>>(W_msg, wmsg, 1024 * 256);
    k_convert<<<256, 256, 0, stream>>>(w_ih + 512 * 256, win, 256 * 256);
    k_convert<<<256, 256, 0, stream>>>(w_hh + 512 * 256, whn, 256 * 256);
    k_pack_rz<<<1024, 256, 0, stream>>>(w_ih, w_hh, wrz);
    k_brz<<<2, 256, 0, stream>>>(b_ih, b_hh, brz);
    k_feat<<<MP, 256, 0, stream>>>(feat, ah);

    k_count<<<(EE + 255) / 256, 256, 0, stream>>>(dst, cnt);
    k_scan<<<1, 1024, 0, stream>>>(cnt, rowptr, cur);
    k_fill<<<(EE + 255) / 256, 256, 0, stream>>>(src, dst, etype, cur, colpk);

    for (int s = 0; s < 5; ++s) {
        // Wh = h * W_msg^T  [MP x 1024] fp16
        gemm_f16_o16<<<dim3(8, MP / 128), 256, 0, stream>>>(
            ah + 256, 512, wmsg, 256, b_msg, Wh, 1024, 8);
        k_agg<<<MP, 256, 0, stream>>>(Wh, rowptr, colpk, ah);
        // rsum|zsum = [a|h] * wrz^T (K=512) -> G cols 0..511
        gemm_f16<<<dim3(4, MP / 128), 256, 0, stream>>>(
            ah, 512, wrz, 512, brz, G, 1024, 16);
        // i_n = a * w_in^T (K=256) -> G cols 512..767
        gemm_f16<<<dim3(2, MP / 128), 256, 0, stream>>>(
            ah, 512, win, 256, b_ih + 512, G + 512, 1024, 8);
        // h_n = h * w_hn^T (K=256) -> G cols 768..1023
        gemm_f16<<<dim3(2, MP / 128), 256, 0, stream>>>(
            ah + 256, 512, whn, 256, b_hh + 512, G + 768, 1024, 8);
        k_gru<<<MP, 256, 0, stream>>>(G, ah);
    }

    k_elu_stats<<<235, 256, 0, stream>>>(ah, h2, bnsum, bnsq);
    k_prep<<<1, 256, 0, stream>>>(bnsum, bnsq, bn_g, bn_b, gatew, gateb, wp);
    k_gate<<<235, 256, 0, stream>>>(h2, wp, n2g, gate, gmaxenc);
    k_expden<<<(NN + 255) / 256, 256, 0, stream>>>(gate, n2g, gmaxenc, denom);
    k_pool<<<235, 256, 0, stream>>>(h2, gate, denom, n2g, h_g);
    k_cls<<<GG, 256, 0, stream>>>(h_g, bnsum, bnsq, bn_g, bn_b, W1, b1, W2, b2, out);

    (void)in_sizes; (void)n_in; (void)out_size; (void)ws_size;
}

// Round 7
// 1091.858 us; speedup vs baseline: 2.0409x; 1.0599x over previous
//
#include <hip/hip_runtime.h>

#define NN 30000
#define EE 480000
#define HH 256
#define TT 4
#define GG 64
#define CC 10
#define MP 30080   // 235 * 128, padded rows
#define SCAN_B 30  // ceil(NN/1024)

typedef unsigned short u16;
typedef unsigned int u32;
typedef _Float16 f16;
typedef f16 half8 __attribute__((ext_vector_type(8)));
typedef f16 half4 __attribute__((ext_vector_type(4)));
typedef float f32x4 __attribute__((ext_vector_type(4)));

// ---------- helpers ----------
__device__ __forceinline__ u32 encf(float x) {       // order-preserving float->uint
    u32 u = __float_as_uint(x);
    return (u & 0x80000000u) ? ~u : (u | 0x80000000u);
}
__device__ __forceinline__ float decf(u32 e) {
    u32 u = (e & 0x80000000u) ? (e ^ 0x80000000u) : ~e;
    return __uint_as_float(u);
}
__device__ __forceinline__ void gl_lds16(const void* g, void* l) {
    __builtin_amdgcn_global_load_lds(
        (const __attribute__((address_space(1))) void*)g,
        (__attribute__((address_space(3))) void*)l, 16, 0, 0);
}

// ---------- conversion / packing kernels ----------
__global__ void k_convert(const float* __restrict__ in, f16* __restrict__ o, int n) {
    int i = blockIdx.x * 256 + threadIdx.x;
    if (i < n) o[i] = (f16)in[i];
}

// wrz[j][k] = k<256 ? w_ih[j][k] : w_hh[j][k-256]   (j<512: r,z rows)
__global__ void k_pack_rz(const float* __restrict__ w_ih, const float* __restrict__ w_hh,
                          f16* __restrict__ o) {
    int i = blockIdx.x * 256 + threadIdx.x;   // over 512*512
    int j = i >> 9, k = i & 511;
    o[i] = (f16)((k < 256) ? w_ih[j * 256 + k] : w_hh[j * 256 + (k - 256)]);
}

__global__ void k_brz(const float* __restrict__ b_ih, const float* __restrict__ b_hh,
                      float* __restrict__ brz) {
    int j = threadIdx.x + blockIdx.x * 256;
    if (j < 512) brz[j] = b_ih[j] + b_hh[j];
}

// h state -> ah cols 256..511. Padded rows = 0.
__global__ __launch_bounds__(256) void k_feat(const float* __restrict__ feat,
                                              f16* __restrict__ ah) {
    int n = blockIdx.x, c = threadIdx.x;
    float v = (n < NN) ? feat[(size_t)n * HH + c] : 0.f;
    ah[(size_t)n * 512 + 256 + c] = (f16)v;
}

// ---------- CSR build ----------
__global__ void k_count(const int* __restrict__ dst, int* __restrict__ cnt) {
    int e = blockIdx.x * 256 + threadIdx.x;
    if (e < EE) atomicAdd(&cnt[dst[e]], 1);
}

// phase 1: per-1024-chunk local exclusive scan + chunk totals
__global__ __launch_bounds__(1024) void k_scan1(const int* __restrict__ cnt,
                                                int* __restrict__ rowptr,
                                                int* __restrict__ bsum) {
    __shared__ int buf[1024];
    int b = blockIdx.x, tid = threadIdx.x;
    int idx = b * 1024 + tid;
    int x = (idx < NN) ? cnt[idx] : 0;
    buf[tid] = x;
    __syncthreads();
    for (int ofs = 1; ofs < 1024; ofs <<= 1) {
        int v = (tid >= ofs) ? buf[tid - ofs] : 0;
        __syncthreads();
        buf[tid] += v;
        __syncthreads();
    }
    if (idx < NN) rowptr[idx] = buf[tid] - x;
    if (tid == 1023) bsum[b] = buf[1023];
}

// phase 2: exclusive scan over the 30 chunk totals (in place)
__global__ void k_scan2(int* __restrict__ bsum) {
    __shared__ int s[SCAN_B];
    int tid = threadIdx.x;
    if (tid < SCAN_B) s[tid] = bsum[tid];
    __syncthreads();
    if (tid == 0) {
        int run = 0;
        for (int i = 0; i < SCAN_B; ++i) { int v = s[i]; s[i] = run; run += v; }
    }
    __syncthreads();
    if (tid < SCAN_B) bsum[tid] = s[tid];
}

// phase 3: add chunk offsets, produce rowptr + cur
__global__ __launch_bounds__(1024) void k_scan3(int* __restrict__ rowptr,
                                                const int* __restrict__ bsum,
                                                int* __restrict__ cur) {
    int b = blockIdx.x, tid = threadIdx.x;
    int idx = b * 1024 + tid;
    if (idx < NN) {
        int v = rowptr[idx] + bsum[b];
        rowptr[idx] = v;
        cur[idx] = v;
    }
    if (idx == 0) rowptr[NN] = EE;
}

__global__ void k_fill(const int* __restrict__ src, const int* __restrict__ dst,
                       const int* __restrict__ et, int* __restrict__ cur,
                       int* __restrict__ colpk) {
    int e = blockIdx.x * 256 + threadIdx.x;
    if (e < EE) {
        int pos = atomicAdd(&cur[dst[e]], 1);
        colpk[pos] = (et[e] << 16) | src[e];
    }
}

// ---------- fp16 MFMA GEMM, BK=64, XOR-swizzled LDS ----------
// C[128y x 128x] = A[. x K] * B[. x K]^T + bias.  KT = K/64.
// LDS tile: 128 rows x 64 halves (128 B/row). Chunk (8 halves = 16 B) at row r,
// chunk c stored at position p = c ^ (r & 7)  -> conflict-free b128 reads.
__global__ __launch_bounds__(256) void gemm_f16(
    const f16* __restrict__ A, int lda,
    const f16* __restrict__ B, int ldb,
    const float* __restrict__ bias, float* __restrict__ C, int ldc, int KT) {
    __shared__ f16 sA[8192], sB[8192];
    const int tid = threadIdx.x;
    const int lane = tid & 63;
    const int wv = tid >> 6;
    const int wr = wv >> 1, wc = wv & 1;
    const int m0 = blockIdx.y * 128, n0 = blockIdx.x * 128;

    const int ldRow = tid >> 3;                         // 0..31
    const int ldK = ((tid & 7) ^ (ldRow & 7)) * 8;      // swizzled source chunk
    const f16* aP = A + (size_t)(m0 + ldRow) * lda + ldK;
    const f16* bP = B + (size_t)(n0 + ldRow) * ldb + ldK;
    const size_t rstepA = (size_t)32 * lda;
    const size_t rstepB = (size_t)32 * ldb;

    const int wbyte = (tid & ~63) * 16;   // wave-uniform LDS base (lane0 of wave)
    char* dA = (char*)sA + wbyte;
    char* dB = (char*)sB + wbyte;

    f32x4 acc[4][4];
#pragma unroll
    for (int i = 0; i < 4; i++)
#pragma unroll
        for (int j = 0; j < 4; j++) acc[i][j] = {0.f, 0.f, 0.f, 0.f};

    const int fr = lane & 15;
    const int l7 = lane & 7;
    const int cq = lane >> 4;                 // 0..3
    const int p0 = (cq ^ l7) * 8;             // kk=0 sub-tile position
    const int p1 = ((cq + 4) ^ l7) * 8;       // kk=32 sub-tile position

    for (int kt = 0; kt < KT; ++kt) {
        const int k0 = kt * 64;
        __syncthreads();
        gl_lds16(aP + k0, dA);
        gl_lds16(aP + k0 + rstepA, dA + 4096);
        gl_lds16(aP + k0 + 2 * rstepA, dA + 8192);
        gl_lds16(aP + k0 + 3 * rstepA, dA + 12288);
        gl_lds16(bP + k0, dB);
        gl_lds16(bP + k0 + rstepB, dB + 4096);
        gl_lds16(bP + k0 + 2 * rstepB, dB + 8192);
        gl_lds16(bP + k0 + 3 * rstepB, dB + 12288);
        __syncthreads();

#pragma unroll
        for (int kk = 0; kk < 2; ++kk) {
            const int p = kk ? p1 : p0;
            half8 bh[4];
#pragma unroll
            for (int j = 0; j < 4; j++) {
                int brow = wc * 64 + j * 16 + fr;
                bh[j] = *(const half8*)&sB[brow * 64 + p];
            }
#pragma unroll
            for (int i = 0; i < 4; i++) {
                int arow = wr * 64 + i * 16 + fr;
                half8 ah = *(const half8*)&sA[arow * 64 + p];
#pragma unroll
                for (int j = 0; j < 4; j++)
                    acc[i][j] = __builtin_amdgcn_mfma_f32_16x16x32_f16(ah, bh[j], acc[i][j], 0, 0, 0);
            }
        }
    }

    // C/D layout (verified m89/m91): col = lane&15, row = (lane>>4)*4 + reg
    const int lr = (lane >> 4) * 4;
    const int lc = lane & 15;
#pragma unroll
    for (int j = 0; j < 4; j++) {
        const int col = n0 + wc * 64 + j * 16 + lc;
        const float bj = bias[col];
#pragma unroll
        for (int i = 0; i < 4; i++) {
            const int rb = m0 + wr * 64 + i * 16 + lr;
#pragma unroll
            for (int r = 0; r < 4; r++)
                C[(size_t)(rb + r) * ldc + col] = acc[i][j][r] + bj;
        }
    }
}

// same GEMM but fp16 output (for Wh)
__global__ __launch_bounds__(256) void gemm_f16_o16(
    const f16* __restrict__ A, int lda,
    const f16* __restrict__ B, int ldb,
    const float* __restrict__ bias, f16* __restrict__ C, int ldc, int KT) {
    __shared__ f16 sA[8192], sB[8192];
    const int tid = threadIdx.x;
    const int lane = tid & 63;
    const int wv = tid >> 6;
    const int wr = wv >> 1, wc = wv & 1;
    const int m0 = blockIdx.y * 128, n0 = blockIdx.x * 128;

    const int ldRow = tid >> 3;
    const int ldK = ((tid & 7) ^ (ldRow & 7)) * 8;
    const f16* aP = A + (size_t)(m0 + ldRow) * lda + ldK;
    const f16* bP = B + (size_t)(n0 + ldRow) * ldb + ldK;
    const size_t rstepA = (size_t)32 * lda;
    const size_t rstepB = (size_t)32 * ldb;

    const int wbyte = (tid & ~63) * 16;
    char* dA = (char*)sA + wbyte;
    char* dB = (char*)sB + wbyte;

    f32x4 acc[4][4];
#pragma unroll
    for (int i = 0; i < 4; i++)
#pragma unroll
        for (int j = 0; j < 4; j++) acc[i][j] = {0.f, 0.f, 0.f, 0.f};

    const int fr = lane & 15;
    const int l7 = lane & 7;
    const int cq = lane >> 4;
    const int p0 = (cq ^ l7) * 8;
    const int p1 = ((cq + 4) ^ l7) * 8;

    for (int kt = 0; kt < KT; ++kt) {
        const int k0 = kt * 64;
        __syncthreads();
        gl_lds16(aP + k0, dA);
        gl_lds16(aP + k0 + rstepA, dA + 4096);
        gl_lds16(aP + k0 + 2 * rstepA, dA + 8192);
        gl_lds16(aP + k0 + 3 * rstepA, dA + 12288);
        gl_lds16(bP + k0, dB);
        gl_lds16(bP + k0 + rstepB, dB + 4096);
        gl_lds16(bP + k0 + 2 * rstepB, dB + 8192);
        gl_lds16(bP + k0 + 3 * rstepB, dB + 12288);
        __syncthreads();

#pragma unroll
        for (int kk = 0; kk < 2; ++kk) {
            const int p = kk ? p1 : p0;
            half8 bh[4];
#pragma unroll
            for (int j = 0; j < 4; j++) {
                int brow = wc * 64 + j * 16 + fr;
                bh[j] = *(const half8*)&sB[brow * 64 + p];
            }
#pragma unroll
            for (int i = 0; i < 4; i++) {
                int arow = wr * 64 + i * 16 + fr;
                half8 ah = *(const half8*)&sA[arow * 64 + p];
#pragma unroll
                for (int j = 0; j < 4; j++)
                    acc[i][j] = __builtin_amdgcn_mfma_f32_16x16x32_f16(ah, bh[j], acc[i][j], 0, 0, 0);
            }
        }
    }

    const int lr = (lane >> 4) * 4;
    const int lc = lane & 15;
#pragma unroll
    for (int j = 0; j < 4; j++) {
        const int col = n0 + wc * 64 + j * 16 + lc;
        const float bj = bias[col];
#pragma unroll
        for (int i = 0; i < 4; i++) {
            const int rb = m0 + wr * 64 + i * 16 + lr;
#pragma unroll
            for (int r = 0; r < 4; r++)
                C[(size_t)(rb + r) * ldc + col] = (f16)(acc[i][j][r] + bj);
        }
    }
}

// ---------- per-dst aggregation (pull via CSR, latency-hidden) -> ah cols 0..255 ----------
// 64 lanes x 4 edge-strips; each lane covers 4 cols via f16x4 loads; colpk staged in LDS.
__global__ __launch_bounds__(256) void k_agg(const f16* __restrict__ Wh,
                                             const int* __restrict__ rowptr,
                                             const int* __restrict__ colpk,
                                             f16* __restrict__ ah) {
    __shared__ int spk[256];
    __shared__ float4 sacc[3][64];
    const int n = blockIdx.x;
    const int tid = threadIdx.x;
    const int col4 = tid & 63;         // cols 4*col4 .. 4*col4+3
    const int strip = tid >> 6;        // 0..3 (== wave id)
    float4 acc = {0.f, 0.f, 0.f, 0.f};

    if (n < NN) {
        const int e0 = rowptr[n], e1 = rowptr[n + 1];
        for (int base = e0; base < e1; base += 256) {
            const int chunk = min(256, e1 - base);
            __syncthreads();
            if (tid < chunk) spk[tid] = colpk[base + tid];
            __syncthreads();
            int i = strip;
            // 2x unroll: 2 independent loads in flight per thread (8 edges/block)
            for (; i + 4 < chunk; i += 8) {
                const int pk0 = spk[i], pk1 = spk[i + 4];
                const half4 v0 = *(const half4*)&Wh[(size_t)(pk0 & 0xFFFF) * 1024 + (pk0 >> 16) * 256 + col4 * 4];
                const half4 v1 = *(const half4*)&Wh[(size_t)(pk1 & 0xFFFF) * 1024 + (pk1 >> 16) * 256 + col4 * 4];
                acc.x += (float)v0.x + (float)v1.x;
                acc.y += (float)v0.y + (float)v1.y;
                acc.z += (float)v0.z + (float)v1.z;
                acc.w += (float)v0.w + (float)v1.w;
            }
            for (; i < chunk; i += 4) {
                const int pk = spk[i];
                const half4 v = *(const half4*)&Wh[(size_t)(pk & 0xFFFF) * 1024 + (pk >> 16) * 256 + col4 * 4];
                acc.x += (float)v.x;
                acc.y += (float)v.y;
                acc.z += (float)v.z;
                acc.w += (float)v.w;
            }
        }
    }
    if (strip) sacc[strip - 1][col4] = acc;
    __syncthreads();
    if (strip == 0 && n < NN) {
        const float4 t0 = sacc[0][col4], t1 = sacc[1][col4], t2 = sacc[2][col4];
        half4 o;
        o.x = (f16)(acc.x + t0.x + t1.x + t2.x);
        o.y = (f16)(acc.y + t0.y + t1.y + t2.y);
        o.z = (f16)(acc.z + t0.z + t1.z + t2.z);
        o.w = (f16)(acc.w + t0.w + t1.w + t2.w);
        *(half4*)&ah[(size_t)n * 512 + col4 * 4] = o;
    }
}

// ---------- GRU cell elementwise: G = [rsum(256)|zsum(256)|i_n(256)|h_n(256)] ----------
__global__ __launch_bounds__(256) void k_gru(const float* __restrict__ G,
                                             f16* __restrict__ ah) {
    int n = blockIdx.x, c = threadIdx.x;
    size_t b = (size_t)n * 1024 + c;
    float rsum = G[b], zsum = G[b + 256], inn = G[b + 512], hn = G[b + 768];
    float r = 1.f / (1.f + expf(-rsum));
    float z = 1.f / (1.f + expf(-zsum));
    float nn = tanhf(inn + r * hn);
    size_t i = (size_t)n * 512 + 256 + c;
    float hv = (float)ah[i];
    float o = (1.f - z) * nn + z * hv;
    ah[i] = (f16)o;
}

// ---------- tail: elu + BN stats (h2 = raw elu output, f32) ----------
__global__ __launch_bounds__(256) void k_elu_stats(const f16* __restrict__ ah,
                                                   float* __restrict__ h2,
                                                   float* __restrict__ bnsum,
                                                   float* __restrict__ bnsq) {
    int c = threadIdx.x;
    int r0 = blockIdx.x * 128;
    int r1 = min(r0 + 128, NN);
    float s = 0.f, q = 0.f;
    for (int n = r0; n < r1; ++n) {
        float x = (float)ah[(size_t)n * 512 + 256 + c];
        float e = x > 0.f ? x : expm1f(x);
        h2[(size_t)n * HH + c] = e;
        s += e;
        q += e * e;
    }
    atomicAdd(&bnsum[c], s);
    atomicAdd(&bnsq[c], q);
}

// ---------- fold BN affine into gate weights: wp[0..255], wp[256]=const ----------
__global__ __launch_bounds__(256) void k_prep(const float* __restrict__ bnsum,
                                              const float* __restrict__ bnsq,
                                              const float* __restrict__ gamma,
                                              const float* __restrict__ beta,
                                              const float* __restrict__ gate_w,
                                              const float* __restrict__ gate_b,
                                              float* __restrict__ wp) {
    __shared__ float red[256];
    int c = threadIdx.x;
    float mu = bnsum[c] * (1.f / NN);
    float var = bnsq[c] * (1.f / NN) - mu * mu;
    float rs = rsqrtf(var + 1e-5f);
    float gm = gamma[c], w = gate_w[c];
    wp[c] = rs * gm * w;
    red[c] = (beta[c] - mu * rs * gm) * w;
    __syncthreads();
    for (int st = 128; st > 0; st >>= 1) {
        if (c < st) red[c] += red[c + st];
        __syncthreads();
    }
    if (c == 0) wp[256] = red[0] + gate_b[0];
}

// ---------- gate score: wave dots, LDS-staged segment max (few global atomics) ----------
__global__ __launch_bounds__(256) void k_gate(const float* __restrict__ h2,
                                              const float* __restrict__ wp,
                                              const int* __restrict__ n2g,
                                              float* __restrict__ gate,
                                              u32* __restrict__ gmaxenc) {
    __shared__ u32 smax[64];
    int tid = threadIdx.x;
    if (tid < 64) smax[tid] = 0;
    __syncthreads();
    int lane = tid & 63, wv = tid >> 6;
    int base = blockIdx.x * 128 + wv * 32;       // each wave: 32 consecutive nodes
    float4 w = ((const float4*)wp)[lane];
    float wc = wp[256];
    for (int k = 0; k < 32; ++k) {
        int n = base + k;
        if (n >= NN) break;
        float4 v = ((const float4*)(h2 + (size_t)n * HH))[lane];
        float s = v.x * w.x + v.y * w.y + v.z * w.z + v.w * w.w;
#pragma unroll
        for (int off = 32; off; off >>= 1) s += __shfl_down(s, off);
        if (lane == 0) {
            float gt = s + wc;
            gate[n] = gt;
            atomicMax(&smax[n2g[n]], encf(gt));
        }
    }
    __syncthreads();
    if (tid < 64 && smax[tid]) atomicMax(&gmaxenc[tid], smax[tid]);
}

// ---------- exp + denom (LDS-staged segment sum) ----------
__global__ void k_expden(float* __restrict__ gate,
                         const int* __restrict__ n2g,
                         const u32* __restrict__ gmaxenc,
                         float* __restrict__ denom) {
    __shared__ float ssum[64];
    int tid = threadIdx.x;
    if (tid < 64) ssum[tid] = 0.f;
    __syncthreads();
    int n = blockIdx.x * 256 + tid;
    if (n < NN) {
        int g = n2g[n];
        float e = expf(gate[n] - decf(gmaxenc[g]));
        gate[n] = e;
        atomicAdd(&ssum[g], e);
    }
    __syncthreads();
    if (tid < 64 && ssum[tid] != 0.f) atomicAdd(&denom[tid], ssum[tid]);
}

// ---------- attention pooling over RAW h2 (n2g sorted; flush on graph change) ----------
__global__ __launch_bounds__(256) void k_pool(const float* __restrict__ h2,
                                              const float* __restrict__ gate,
                                              const float* __restrict__ denom,
                                              const int* __restrict__ n2g,
                                              float* __restrict__ h_g) {
    int c = threadIdx.x;
    int r0 = blockIdx.x * 128, r1 = min(r0 + 128, NN);
    int gcur = -1;
    float accv = 0.f, inv = 0.f;
    for (int n = r0; n < r1; ++n) {
        int g = n2g[n];
        if (g != gcur) {
            if (gcur >= 0) atomicAdd(&h_g[gcur * HH + c], accv);
            gcur = g;
            accv = 0.f;
            inv = 1.f / denom[g];
        }
        accv += gate[n] * inv * h2[(size_t)n * HH + c];
    }
    if (gcur >= 0) atomicAdd(&h_g[gcur * HH + c], accv);
}

// ---------- classifier (applies BN affine to pooled vector) ----------
__global__ __launch_bounds__(256) void k_cls(const float* __restrict__ h_g,
                                             const float* __restrict__ bnsum,
                                             const float* __restrict__ bnsq,
                                             const float* __restrict__ gamma,
                                             const float* __restrict__ beta,
                                             const float* __restrict__ W1,
                                             const float* __restrict__ b1,
                                             const float* __restrict__ W2,
                                             const float* __restrict__ b2,
                                             float* __restrict__ out) {
    __shared__ float hg[256];
    __shared__ float x1[128];
    int g = blockIdx.x, tid = threadIdx.x;
    float mu = bnsum[tid] * (1.f / NN);
    float var = bnsq[tid] * (1.f / NN) - mu * mu;
    hg[tid] = (h_g[g * HH + tid] - mu) * rsqrtf(var + 1e-5f) * gamma[tid] + beta[tid];
    __syncthreads();
    if (tid < 128) {
        const float* w = W1 + tid * 256;
        float s = b1[tid];
#pragma unroll 8
        for (int c = 0; c < 256; ++c) s += hg[c] * w[c];
        x1[tid] = fmaxf(s, 0.f);
    }
    __syncthreads();
    if (tid < 10) {
        const float* w = W2 + tid * 128;
        float s = b2[tid];
        for (int j = 0; j < 128; ++j) s += x1[j] * w[j];
        out[g * CC + tid] = s;
    }
}

// =======================================================================
extern "C" void kernel_launch(void* const* d_in, const int* in_sizes, int n_in,
                              void* d_out, int out_size, void* d_ws, size_t ws_size,
                              hipStream_t stream) {
    const float* feat  = (const float*)d_in[0];
    const int*   src   = (const int*)d_in[1];
    const int*   dst   = (const int*)d_in[2];
    const int*   etype = (const int*)d_in[3];
    const int*   n2g   = (const int*)d_in[4];
    const float* W_msg = (const float*)d_in[5];
    const float* b_msg = (const float*)d_in[6];
    const float* w_ih  = (const float*)d_in[7];
    const float* w_hh  = (const float*)d_in[8];
    const float* b_ih  = (const float*)d_in[9];
    const float* b_hh  = (const float*)d_in[10];
    const float* bn_g  = (const float*)d_in[11];
    const float* bn_b  = (const float*)d_in[12];
    const float* gatew = (const float*)d_in[13];
    const float* gateb = (const float*)d_in[14];
    const float* W1    = (const float*)d_in[15];
    const float* b1    = (const float*)d_in[16];
    const float* W2    = (const float*)d_in[17];
    const float* b2    = (const float*)d_in[18];
    float* out = (float*)d_out;

    char* ws = (char*)d_ws;
    size_t off = 0;
    auto alloc = [&](size_t bytes) -> char* {
        char* p = ws + off;
        off += (bytes + 255) & ~(size_t)255;
        return p;
    };

    // zero zone (single memset): cnt | bnsum | bnsq | denom | gmaxenc | h_g
    const size_t ZZ = (size_t)(NN + 256 + 256 + 64 + 64 + GG * HH) * 4;
    char* zz = alloc(ZZ);
    int*   cnt     = (int*)zz;
    float* bnsum   = (float*)(zz + (size_t)NN * 4);
    float* bnsq    = bnsum + 256;
    float* denom   = bnsq + 256;
    u32*   gmaxenc = (u32*)(denom + 64);
    float* h_g     = (float*)(gmaxenc + 64);

    int* rowptr = (int*)alloc((NN + 1) * 4);
    int* cur    = (int*)alloc(NN * 4);
    int* bsum   = (int*)alloc(SCAN_B * 4);
    int* colpk  = (int*)alloc((size_t)EE * 4);
    float* gate = (float*)alloc(NN * 4);
    float* wp   = (float*)alloc(260 * 4);

    // interleaved node state: cols 0..255 = a, cols 256..511 = h (fp16)
    f16* ah = (f16*)alloc((size_t)MP * 512 * 2);

    f16* wmsg = (f16*)alloc((size_t)1024 * 256 * 2);
    f16* wrz  = (f16*)alloc((size_t)512 * 512 * 2);
    f16* win  = (f16*)alloc((size_t)256 * 256 * 2);
    f16* whn  = (f16*)alloc((size_t)256 * 256 * 2);
    float* brz = (float*)alloc(512 * 4);

    // big region: G f32 [MP x 1024]; Wh fp16 [MP x 1024] and h2 f32 [MP x 256] overlap it
    char* big = alloc((size_t)MP * 1024 * 4);
    float* G  = (float*)big;
    f16*   Wh = (f16*)big;
    float* h2 = (float*)big;

    hipMemsetAsync(zz, 0, ZZ, stream);

    k_convert<<<1024, 256, 0, stream>>>(W_msg, wmsg, 1024 * 256);
    k_convert<<<256, 256, 0, stream>>>(w_ih + 512 * 256, win, 256 * 256);
    k_convert<<<256, 256, 0, stream>>>(w_hh + 512 * 256, whn, 256 * 256);
    k_pack_rz<<<1024, 256, 0, stream>>>(w_ih, w_hh, wrz);
    k_brz<<<2, 256, 0, stream>>>(b_ih, b_hh, brz);
    k_feat<<<MP, 256, 0, stream>>>(feat, ah);

    k_count<<<(EE + 255) / 256, 256, 0, stream>>>(dst, cnt);
    k_scan1<<<SCAN_B, 1024, 0, stream>>>(cnt, rowptr, bsum);
    k_scan2<<<1, 64, 0, stream>>>(bsum);
    k_scan3<<<SCAN_B, 1024, 0, stream>>>(rowptr, bsum, cur);
    k_fill<<<(EE + 255) / 256, 256, 0, stream>>>(src, dst, etype, cur, colpk);

    for (int s = 0; s < 5; ++s) {
        // Wh = h * W_msg^T  [MP x 1024] fp16   (K=256 -> KT=4)
        gemm_f16_o16<<<dim3(8, MP / 128), 256, 0, stream>>>(
            ah + 256, 512, wmsg, 256, b_msg, Wh, 1024, 4);
        k_agg<<<MP, 256, 0, stream>>>(Wh, rowptr, colpk, ah);
        // rsum|zsum = [a|h] * wrz^T (K=512 -> KT=8) -> G cols 0..511
        gemm_f16<<<dim3(4, MP / 128), 256, 0, stream>>>(
            ah, 512, wrz, 512, brz, G, 1024, 8);
        // i_n = a * w_in^T (K=256 -> KT=4) -> G cols 512..767
        gemm_f16<<<dim3(2, MP / 128), 256, 0, stream>>>(
            ah, 512, win, 256, b_ih + 512, G + 512, 1024, 4);
        // h_n = h * w_hn^T (K=256 -> KT=4) -> G cols 768..1023
        gemm_f16<<<dim3(2, MP / 128), 256, 0, stream>>>(
            ah + 256, 512, whn, 256, b_hh + 512, G + 768, 1024, 4);
        k_gru<<<MP, 256, 0, stream>>>(G, ah);
    }

    k_elu_stats<<<235, 256, 0, stream>>>(ah, h2, bnsum, bnsq);
    k_prep<<<1, 256, 0, stream>>>(bnsum, bnsq, bn_g, bn_b, gatew, gateb, wp);
    k_gate<<<235, 256, 0, stream>>>(h2, wp, n2g, gate, gmaxenc);
    k_expden<<<(NN + 255) / 256, 256, 0, stream>>>(gate, n2g, gmaxenc, denom);
    k_pool<<<235, 256, 0, stream>>>(h2, gate, denom, n2g, h_g);
    k_cls<<<GG, 256, 0, stream>>>(h_g, bnsum, bnsq, bn_g, bn_b, W1, b1, W2, b2, out);

    (void)in_sizes; (void)n_in; (void)out_size; (void)ws_size;
}

// Round 8
// 1080.262 us; speedup vs baseline: 2.0628x; 1.0107x over previous
//
#include <hip/hip_runtime.h>

#define NN 30000
#define EE 480000
#define HH 256
#define TT 4
#define GG 64
#define CC 10
#define MP 30080   // 235 * 128, padded rows
#define SCAN_B 30  // ceil(NN/1024)

typedef unsigned short u16;
typedef unsigned int u32;
typedef _Float16 f16;
typedef f16 half8 __attribute__((ext_vector_type(8)));
typedef f16 half4 __attribute__((ext_vector_type(4)));
typedef float f32x4 __attribute__((ext_vector_type(4)));

// ---------- helpers ----------
__device__ __forceinline__ u32 encf(float x) {       // order-preserving float->uint
    u32 u = __float_as_uint(x);
    return (u & 0x80000000u) ? ~u : (u | 0x80000000u);
}
__device__ __forceinline__ float decf(u32 e) {
    u32 u = (e & 0x80000000u) ? (e ^ 0x80000000u) : ~e;
    return __uint_as_float(u);
}
__device__ __forceinline__ void gl_lds16(const void* g, void* l) {
    __builtin_amdgcn_global_load_lds(
        (const __attribute__((address_space(1))) void*)g,
        (__attribute__((address_space(3))) void*)l, 16, 0, 0);
}

// ---------- conversion / packing kernels ----------
__global__ void k_convert(const float* __restrict__ in, f16* __restrict__ o, int n) {
    int i = blockIdx.x * 256 + threadIdx.x;
    if (i < n) o[i] = (f16)in[i];
}

// packed GRU weight wG [1024 x 512]:
//   rows 0..511  : [w_ih_rz | w_hh_rz]           (read with K=[0,512))
//   rows 512..767: [w_ih_n  | 0      ]           (read with K=[0,256))
//   rows 768..1023:[0       | w_hh_n ]           (read with K=[256,512))
__global__ void k_pack_G(const float* __restrict__ w_ih, const float* __restrict__ w_hh,
                         f16* __restrict__ o) {
    int i = blockIdx.x * 256 + threadIdx.x;   // over 1024*512
    int j = i >> 9, k = i & 511;
    float v;
    if (j < 512)       v = (k < 256) ? w_ih[j * 256 + k] : w_hh[j * 256 + (k - 256)];
    else if (j < 768)  v = (k < 256) ? w_ih[j * 256 + k] : 0.f;
    else               v = (k >= 256) ? w_hh[(j - 256) * 256 + (k - 256)] : 0.f;
    o[i] = (f16)v;
}

__global__ void k_bias(const float* __restrict__ b_ih, const float* __restrict__ b_hh,
                       float* __restrict__ bG) {
    int j = threadIdx.x + blockIdx.x * 256;
    if (j < 512)       bG[j] = b_ih[j] + b_hh[j];
    else if (j < 768)  bG[j] = b_ih[j];
    else if (j < 1024) bG[j] = b_hh[j - 256];
}

// h state -> ah cols 256..511. Padded rows = 0.
__global__ __launch_bounds__(256) void k_feat(const float* __restrict__ feat,
                                              f16* __restrict__ ah) {
    int n = blockIdx.x, c = threadIdx.x;
    float v = (n < NN) ? feat[(size_t)n * HH + c] : 0.f;
    ah[(size_t)n * 512 + 256 + c] = (f16)v;
}

// ---------- CSR build ----------
__global__ void k_count(const int* __restrict__ dst, int* __restrict__ cnt) {
    int e = blockIdx.x * 256 + threadIdx.x;
    if (e < EE) atomicAdd(&cnt[dst[e]], 1);
}

__global__ __launch_bounds__(1024) void k_scan1(const int* __restrict__ cnt,
                                                int* __restrict__ rowptr,
                                                int* __restrict__ bsum) {
    __shared__ int buf[1024];
    int b = blockIdx.x, tid = threadIdx.x;
    int idx = b * 1024 + tid;
    int x = (idx < NN) ? cnt[idx] : 0;
    buf[tid] = x;
    __syncthreads();
    for (int ofs = 1; ofs < 1024; ofs <<= 1) {
        int v = (tid >= ofs) ? buf[tid - ofs] : 0;
        __syncthreads();
        buf[tid] += v;
        __syncthreads();
    }
    if (idx < NN) rowptr[idx] = buf[tid] - x;
    if (tid == 1023) bsum[b] = buf[1023];
}

__global__ void k_scan2(int* __restrict__ bsum) {
    __shared__ int s[SCAN_B];
    int tid = threadIdx.x;
    if (tid < SCAN_B) s[tid] = bsum[tid];
    __syncthreads();
    if (tid == 0) {
        int run = 0;
        for (int i = 0; i < SCAN_B; ++i) { int v = s[i]; s[i] = run; run += v; }
    }
    __syncthreads();
    if (tid < SCAN_B) bsum[tid] = s[tid];
}

__global__ __launch_bounds__(1024) void k_scan3(int* __restrict__ rowptr,
                                                const int* __restrict__ bsum,
                                                int* __restrict__ cur) {
    int b = blockIdx.x, tid = threadIdx.x;
    int idx = b * 1024 + tid;
    if (idx < NN) {
        int v = rowptr[idx] + bsum[b];
        rowptr[idx] = v;
        cur[idx] = v;
    }
    if (idx == 0) rowptr[NN] = EE;
}

__global__ void k_fill(const int* __restrict__ src, const int* __restrict__ dst,
                       const int* __restrict__ et, int* __restrict__ cur,
                       int* __restrict__ colpk) {
    int e = blockIdx.x * 256 + threadIdx.x;
    if (e < EE) {
        int pos = atomicAdd(&cur[dst[e]], 1);
        colpk[pos] = (et[e] << 16) | src[e];
    }
}

// ---------- fp16 MFMA GEMM, BK=64, XOR-swizzled LDS, fp16 output ----------
// C[128y x 128x] = A[. x K] * B[. x K]^T + bias.  K-range [kt0*64, kt1*64).
__global__ __launch_bounds__(256) void gemm_f16_o16(
    const f16* __restrict__ A, int lda,
    const f16* __restrict__ B, int ldb,
    const float* __restrict__ bias, f16* __restrict__ C, int ldc, int KT) {
    __shared__ f16 sA[8192], sB[8192];
    const int tid = threadIdx.x;
    const int lane = tid & 63;
    const int wv = tid >> 6;
    const int wr = wv >> 1, wc = wv & 1;
    const int m0 = blockIdx.y * 128, n0 = blockIdx.x * 128;

    const int ldRow = tid >> 3;
    const int ldK = ((tid & 7) ^ (ldRow & 7)) * 8;
    const f16* aP = A + (size_t)(m0 + ldRow) * lda + ldK;
    const f16* bP = B + (size_t)(n0 + ldRow) * ldb + ldK;
    const size_t rstepA = (size_t)32 * lda;
    const size_t rstepB = (size_t)32 * ldb;

    const int wbyte = (tid & ~63) * 16;
    char* dA = (char*)sA + wbyte;
    char* dB = (char*)sB + wbyte;

    f32x4 acc[4][4];
#pragma unroll
    for (int i = 0; i < 4; i++)
#pragma unroll
        for (int j = 0; j < 4; j++) acc[i][j] = {0.f, 0.f, 0.f, 0.f};

    const int fr = lane & 15;
    const int l7 = lane & 7;
    const int cq = lane >> 4;
    const int p0 = (cq ^ l7) * 8;
    const int p1 = ((cq + 4) ^ l7) * 8;

    for (int kt = 0; kt < KT; ++kt) {
        const int k0 = kt * 64;
        __syncthreads();
        gl_lds16(aP + k0, dA);
        gl_lds16(aP + k0 + rstepA, dA + 4096);
        gl_lds16(aP + k0 + 2 * rstepA, dA + 8192);
        gl_lds16(aP + k0 + 3 * rstepA, dA + 12288);
        gl_lds16(bP + k0, dB);
        gl_lds16(bP + k0 + rstepB, dB + 4096);
        gl_lds16(bP + k0 + 2 * rstepB, dB + 8192);
        gl_lds16(bP + k0 + 3 * rstepB, dB + 12288);
        __syncthreads();

#pragma unroll
        for (int kk = 0; kk < 2; ++kk) {
            const int p = kk ? p1 : p0;
            half8 bh[4];
#pragma unroll
            for (int j = 0; j < 4; j++) {
                int brow = wc * 64 + j * 16 + fr;
                bh[j] = *(const half8*)&sB[brow * 64 + p];
            }
#pragma unroll
            for (int i = 0; i < 4; i++) {
                int arow = wr * 64 + i * 16 + fr;
                half8 ah = *(const half8*)&sA[arow * 64 + p];
#pragma unroll
                for (int j = 0; j < 4; j++)
                    acc[i][j] = __builtin_amdgcn_mfma_f32_16x16x32_f16(ah, bh[j], acc[i][j], 0, 0, 0);
            }
        }
    }

    const int lr = (lane >> 4) * 4;
    const int lc = lane & 15;
#pragma unroll
    for (int j = 0; j < 4; j++) {
        const int col = n0 + wc * 64 + j * 16 + lc;
        const float bj = bias[col];
#pragma unroll
        for (int i = 0; i < 4; i++) {
            const int rb = m0 + wr * 64 + i * 16 + lr;
#pragma unroll
            for (int r = 0; r < 4; r++)
                C[(size_t)(rb + r) * ldc + col] = (f16)(acc[i][j][r] + bj);
        }
    }
}

// merged GRU GEMM: G[MP x 1024] = [a|h] x wG^T, per-tile K-range.
// tiles 0-3: rz (K 0..511); 4-5: i_n (K 0..255); 6-7: h_n (K 256..511)
__global__ __launch_bounds__(256) void gemm_gru(
    const f16* __restrict__ A,
    const f16* __restrict__ B,
    const float* __restrict__ bias, f16* __restrict__ C) {
    __shared__ f16 sA[8192], sB[8192];
    const int tid = threadIdx.x;
    const int lane = tid & 63;
    const int wv = tid >> 6;
    const int wr = wv >> 1, wc = wv & 1;
    const int m0 = blockIdx.y * 128, n0 = blockIdx.x * 128;
    const int kt0 = (blockIdx.x >= 6) ? 4 : 0;
    const int kt1 = (blockIdx.x >= 4 && blockIdx.x < 6) ? 4 : 8;

    const int ldRow = tid >> 3;
    const int ldK = ((tid & 7) ^ (ldRow & 7)) * 8;
    const f16* aP = A + (size_t)(m0 + ldRow) * 512 + ldK;
    const f16* bP = B + (size_t)(n0 + ldRow) * 512 + ldK;
    const size_t rstep = (size_t)32 * 512;

    const int wbyte = (tid & ~63) * 16;
    char* dA = (char*)sA + wbyte;
    char* dB = (char*)sB + wbyte;

    f32x4 acc[4][4];
#pragma unroll
    for (int i = 0; i < 4; i++)
#pragma unroll
        for (int j = 0; j < 4; j++) acc[i][j] = {0.f, 0.f, 0.f, 0.f};

    const int fr = lane & 15;
    const int l7 = lane & 7;
    const int cq = lane >> 4;
    const int p0 = (cq ^ l7) * 8;
    const int p1 = ((cq + 4) ^ l7) * 8;

    for (int kt = kt0; kt < kt1; ++kt) {
        const int k0 = kt * 64;
        __syncthreads();
        gl_lds16(aP + k0, dA);
        gl_lds16(aP + k0 + rstep, dA + 4096);
        gl_lds16(aP + k0 + 2 * rstep, dA + 8192);
        gl_lds16(aP + k0 + 3 * rstep, dA + 12288);
        gl_lds16(bP + k0, dB);
        gl_lds16(bP + k0 + rstep, dB + 4096);
        gl_lds16(bP + k0 + 2 * rstep, dB + 8192);
        gl_lds16(bP + k0 + 3 * rstep, dB + 12288);
        __syncthreads();

#pragma unroll
        for (int kk = 0; kk < 2; ++kk) {
            const int p = kk ? p1 : p0;
            half8 bh[4];
#pragma unroll
            for (int j = 0; j < 4; j++) {
                int brow = wc * 64 + j * 16 + fr;
                bh[j] = *(const half8*)&sB[brow * 64 + p];
            }
#pragma unroll
            for (int i = 0; i < 4; i++) {
                int arow = wr * 64 + i * 16 + fr;
                half8 ah = *(const half8*)&sA[arow * 64 + p];
#pragma unroll
                for (int j = 0; j < 4; j++)
                    acc[i][j] = __builtin_amdgcn_mfma_f32_16x16x32_f16(ah, bh[j], acc[i][j], 0, 0, 0);
            }
        }
    }

    const int lr = (lane >> 4) * 4;
    const int lc = lane & 15;
#pragma unroll
    for (int j = 0; j < 4; j++) {
        const int col = n0 + wc * 64 + j * 16 + lc;
        const float bj = bias[col];
#pragma unroll
        for (int i = 0; i < 4; i++) {
            const int rb = m0 + wr * 64 + i * 16 + lr;
#pragma unroll
            for (int r = 0; r < 4; r++)
                C[(size_t)(rb + r) * 1024 + col] = (f16)(acc[i][j][r] + bj);
        }
    }
}

// ---------- per-dst aggregation (pull via CSR, latency-hidden) -> ah cols 0..255 ----------
__global__ __launch_bounds__(256) void k_agg(const f16* __restrict__ Wh,
                                             const int* __restrict__ rowptr,
                                             const int* __restrict__ colpk,
                                             f16* __restrict__ ah) {
    __shared__ int spk[256];
    __shared__ float4 sacc[3][64];
    const int n = blockIdx.x;
    const int tid = threadIdx.x;
    const int col4 = tid & 63;
    const int strip = tid >> 6;
    float4 acc = {0.f, 0.f, 0.f, 0.f};

    if (n < NN) {
        const int e0 = rowptr[n], e1 = rowptr[n + 1];
        for (int base = e0; base < e1; base += 256) {
            const int chunk = min(256, e1 - base);
            __syncthreads();
            if (tid < chunk) spk[tid] = colpk[base + tid];
            __syncthreads();
            int i = strip;
            for (; i + 4 < chunk; i += 8) {
                const int pk0 = spk[i], pk1 = spk[i + 4];
                const half4 v0 = *(const half4*)&Wh[(size_t)(pk0 & 0xFFFF) * 1024 + (pk0 >> 16) * 256 + col4 * 4];
                const half4 v1 = *(const half4*)&Wh[(size_t)(pk1 & 0xFFFF) * 1024 + (pk1 >> 16) * 256 + col4 * 4];
                acc.x += (float)v0.x + (float)v1.x;
                acc.y += (float)v0.y + (float)v1.y;
                acc.z += (float)v0.z + (float)v1.z;
                acc.w += (float)v0.w + (float)v1.w;
            }
            for (; i < chunk; i += 4) {
                const int pk = spk[i];
                const half4 v = *(const half4*)&Wh[(size_t)(pk & 0xFFFF) * 1024 + (pk >> 16) * 256 + col4 * 4];
                acc.x += (float)v.x;
                acc.y += (float)v.y;
                acc.z += (float)v.z;
                acc.w += (float)v.w;
            }
        }
    }
    if (strip) sacc[strip - 1][col4] = acc;
    __syncthreads();
    if (strip == 0 && n < NN) {
        const float4 t0 = sacc[0][col4], t1 = sacc[1][col4], t2 = sacc[2][col4];
        half4 o;
        o.x = (f16)(acc.x + t0.x + t1.x + t2.x);
        o.y = (f16)(acc.y + t0.y + t1.y + t2.y);
        o.z = (f16)(acc.z + t0.z + t1.z + t2.z);
        o.w = (f16)(acc.w + t0.w + t1.w + t2.w);
        *(half4*)&ah[(size_t)n * 512 + col4 * 4] = o;
    }
}

// ---------- GRU cell elementwise: G = [rsum|zsum|i_n|h_n] fp16 ----------
__global__ __launch_bounds__(256) void k_gru(const f16* __restrict__ G,
                                             f16* __restrict__ ah) {
    int n = blockIdx.x, c = threadIdx.x;
    size_t b = (size_t)n * 1024 + c;
    float rsum = (float)G[b], zsum = (float)G[b + 256];
    float inn = (float)G[b + 512], hn = (float)G[b + 768];
    float r = 1.f / (1.f + expf(-rsum));
    float z = 1.f / (1.f + expf(-zsum));
    float nn = tanhf(inn + r * hn);
    size_t i = (size_t)n * 512 + 256 + c;
    float hv = (float)ah[i];
    float o = (1.f - z) * nn + z * hv;
    ah[i] = (f16)o;
}

// ---------- tail: elu + BN stats (h2 fp16), 940 blocks x 32 rows ----------
__global__ __launch_bounds__(256) void k_elu_stats(const f16* __restrict__ ah,
                                                   f16* __restrict__ h2,
                                                   float* __restrict__ bnsum,
                                                   float* __restrict__ bnsq) {
    __shared__ float4 ssum[3][64], ssq[3][64];
    int tid = threadIdx.x, lane = tid & 63, w = tid >> 6;
    int c4 = lane * 4;
    float4 s = {0.f, 0.f, 0.f, 0.f}, q = {0.f, 0.f, 0.f, 0.f};
    int r0 = blockIdx.x * 32 + w;
#pragma unroll
    for (int i = 0; i < 8; ++i) {
        int n = r0 + i * 4;
        if (n < NN) {
            half4 v = *(const half4*)&ah[(size_t)n * 512 + 256 + c4];
            float ex = (float)v.x, ey = (float)v.y, ez = (float)v.z, ew = (float)v.w;
            ex = ex > 0.f ? ex : expm1f(ex);
            ey = ey > 0.f ? ey : expm1f(ey);
            ez = ez > 0.f ? ez : expm1f(ez);
            ew = ew > 0.f ? ew : expm1f(ew);
            half4 o; o.x = (f16)ex; o.y = (f16)ey; o.z = (f16)ez; o.w = (f16)ew;
            *(half4*)&h2[(size_t)n * 256 + c4] = o;
            s.x += ex; s.y += ey; s.z += ez; s.w += ew;
            q.x += ex * ex; q.y += ey * ey; q.z += ez * ez; q.w += ew * ew;
        }
    }
    if (w) { ssum[w - 1][lane] = s; ssq[w - 1][lane] = q; }
    __syncthreads();
    if (w == 0) {
#pragma unroll
        for (int k = 0; k < 3; ++k) {
            float4 a = ssum[k][lane], b = ssq[k][lane];
            s.x += a.x; s.y += a.y; s.z += a.z; s.w += a.w;
            q.x += b.x; q.y += b.y; q.z += b.z; q.w += b.w;
        }
        atomicAdd(&bnsum[c4 + 0], s.x); atomicAdd(&bnsum[c4 + 1], s.y);
        atomicAdd(&bnsum[c4 + 2], s.z); atomicAdd(&bnsum[c4 + 3], s.w);
        atomicAdd(&bnsq[c4 + 0], q.x); atomicAdd(&bnsq[c4 + 1], q.y);
        atomicAdd(&bnsq[c4 + 2], q.z); atomicAdd(&bnsq[c4 + 3], q.w);
    }
}

// ---------- fold BN affine into gate weights: wp[0..255], wp[256]=const ----------
__global__ __launch_bounds__(256) void k_prep(const float* __restrict__ bnsum,
                                              const float* __restrict__ bnsq,
                                              const float* __restrict__ gamma,
                                              const float* __restrict__ beta,
                                              const float* __restrict__ gate_w,
                                              const float* __restrict__ gate_b,
                                              float* __restrict__ wp) {
    __shared__ float red[256];
    int c = threadIdx.x;
    float mu = bnsum[c] * (1.f / NN);
    float var = bnsq[c] * (1.f / NN) - mu * mu;
    float rs = rsqrtf(var + 1e-5f);
    float gm = gamma[c], w = gate_w[c];
    wp[c] = rs * gm * w;
    red[c] = (beta[c] - mu * rs * gm) * w;
    __syncthreads();
    for (int st = 128; st > 0; st >>= 1) {
        if (c < st) red[c] += red[c + st];
        __syncthreads();
    }
    if (c == 0) wp[256] = red[0] + gate_b[0];
}

// ---------- gate score: wave dots on fp16 h2, LDS-staged segment max ----------
__global__ __launch_bounds__(256) void k_gate(const f16* __restrict__ h2,
                                              const float* __restrict__ wp,
                                              const int* __restrict__ n2g,
                                              float* __restrict__ gate,
                                              u32* __restrict__ gmaxenc) {
    __shared__ u32 smax[64];
    int tid = threadIdx.x;
    if (tid < 64) smax[tid] = 0;
    __syncthreads();
    int lane = tid & 63, wv = tid >> 6;
    int base = blockIdx.x * 128 + wv * 32;
    float4 w = ((const float4*)wp)[lane];
    float wc = wp[256];
    for (int k = 0; k < 32; ++k) {
        int n = base + k;
        if (n >= NN) break;
        half4 v = *(const half4*)&h2[(size_t)n * HH + lane * 4];
        float s = (float)v.x * w.x + (float)v.y * w.y + (float)v.z * w.z + (float)v.w * w.w;
#pragma unroll
        for (int off = 32; off; off >>= 1) s += __shfl_down(s, off);
        if (lane == 0) {
            float gt = s + wc;
            gate[n] = gt;
            atomicMax(&smax[n2g[n]], encf(gt));
        }
    }
    __syncthreads();
    if (tid < 64 && smax[tid]) atomicMax(&gmaxenc[tid], smax[tid]);
}

// ---------- exp + denom (LDS-staged segment sum) ----------
__global__ void k_expden(float* __restrict__ gate,
                         const int* __restrict__ n2g,
                         const u32* __restrict__ gmaxenc,
                         float* __restrict__ denom) {
    __shared__ float ssum[64];
    int tid = threadIdx.x;
    if (tid < 64) ssum[tid] = 0.f;
    __syncthreads();
    int n = blockIdx.x * 256 + tid;
    if (n < NN) {
        int g = n2g[n];
        float e = expf(gate[n] - decf(gmaxenc[g]));
        gate[n] = e;
        atomicAdd(&ssum[g], e);
    }
    __syncthreads();
    if (tid < 64 && ssum[tid] != 0.f) atomicAdd(&denom[tid], ssum[tid]);
}

// ---------- attention pooling over fp16 h2 (n2g sorted; flush on change) ----------
__global__ __launch_bounds__(256) void k_pool(const f16* __restrict__ h2,
                                              const float* __restrict__ gate,
                                              const float* __restrict__ denom,
                                              const int* __restrict__ n2g,
                                              float* __restrict__ h_g) {
    int c = threadIdx.x;
    int r0 = blockIdx.x * 128, r1 = min(r0 + 128, NN);
    int gcur = -1;
    float accv = 0.f, inv = 0.f;
    for (int n = r0; n < r1; ++n) {
        int g = n2g[n];
        if (g != gcur) {
            if (gcur >= 0) atomicAdd(&h_g[gcur * HH + c], accv);
            gcur = g;
            accv = 0.f;
            inv = 1.f / denom[g];
        }
        accv += gate[n] * inv * (float)h2[(size_t)n * HH + c];
    }
    if (gcur >= 0) atomicAdd(&h_g[gcur * HH + c], accv);
}

// ---------- classifier (applies BN affine to pooled vector) ----------
__global__ __launch_bounds__(256) void k_cls(const float* __restrict__ h_g,
                                             const float* __restrict__ bnsum,
                                             const float* __restrict__ bnsq,
                                             const float* __restrict__ gamma,
                                             const float* __restrict__ beta,
                                             const float* __restrict__ W1,
                                             const float* __restrict__ b1,
                                             const float* __restrict__ W2,
                                             const float* __restrict__ b2,
                                             float* __restrict__ out) {
    __shared__ float hg[256];
    __shared__ float x1[128];
    int g = blockIdx.x, tid = threadIdx.x;
    float mu = bnsum[tid] * (1.f / NN);
    float var = bnsq[tid] * (1.f / NN) - mu * mu;
    hg[tid] = (h_g[g * HH + tid] - mu) * rsqrtf(var + 1e-5f) * gamma[tid] + beta[tid];
    __syncthreads();
    if (tid < 128) {
        const float* w = W1 + tid * 256;
        float s = b1[tid];
#pragma unroll 8
        for (int c = 0; c < 256; ++c) s += hg[c] * w[c];
        x1[tid] = fmaxf(s, 0.f);
    }
    __syncthreads();
    if (tid < 10) {
        const float* w = W2 + tid * 128;
        float s = b2[tid];
        for (int j = 0; j < 128; ++j) s += x1[j] * w[j];
        out[g * CC + tid] = s;
    }
}

// =======================================================================
extern "C" void kernel_launch(void* const* d_in, const int* in_sizes, int n_in,
                              void* d_out, int out_size, void* d_ws, size_t ws_size,
                              hipStream_t stream) {
    const float* feat  = (const float*)d_in[0];
    const int*   src   = (const int*)d_in[1];
    const int*   dst   = (const int*)d_in[2];
    const int*   etype = (const int*)d_in[3];
    const int*   n2g   = (const int*)d_in[4];
    const float* W_msg = (const float*)d_in[5];
    const float* b_msg = (const float*)d_in[6];
    const float* w_ih  = (const float*)d_in[7];
    const float* w_hh  = (const float*)d_in[8];
    const float* b_ih  = (const float*)d_in[9];
    const float* b_hh  = (const float*)d_in[10];
    const float* bn_g  = (const float*)d_in[11];
    const float* bn_b  = (const float*)d_in[12];
    const float* gatew = (const float*)d_in[13];
    const float* gateb = (const float*)d_in[14];
    const float* W1    = (const float*)d_in[15];
    const float* b1    = (const float*)d_in[16];
    const float* W2    = (const float*)d_in[17];
    const float* b2    = (const float*)d_in[18];
    float* out = (float*)d_out;

    char* ws = (char*)d_ws;
    size_t off = 0;
    auto alloc = [&](size_t bytes) -> char* {
        char* p = ws + off;
        off += (bytes + 255) & ~(size_t)255;
        return p;
    };

    // zero zone (single memset): cnt | bnsum | bnsq | denom | gmaxenc | h_g
    const size_t ZZ = (size_t)(NN + 256 + 256 + 64 + 64 + GG * HH) * 4;
    char* zz = alloc(ZZ);
    int*   cnt     = (int*)zz;
    float* bnsum   = (float*)(zz + (size_t)NN * 4);
    float* bnsq    = bnsum + 256;
    float* denom   = bnsq + 256;
    u32*   gmaxenc = (u32*)(denom + 64);
    float* h_g     = (float*)(gmaxenc + 64);

    int* rowptr = (int*)alloc((NN + 1) * 4);
    int* cur    = (int*)alloc(NN * 4);
    int* bsum   = (int*)alloc(SCAN_B * 4);
    int* colpk  = (int*)alloc((size_t)EE * 4);
    float* gate = (float*)alloc(NN * 4);
    float* wp   = (float*)alloc(260 * 4);
    float* bG   = (float*)alloc(1024 * 4);

    // interleaved node state: cols 0..255 = a, cols 256..511 = h (fp16)
    f16* ah = (f16*)alloc((size_t)MP * 512 * 2);

    f16* wmsg = (f16*)alloc((size_t)1024 * 256 * 2);
    f16* wG   = (f16*)alloc((size_t)1024 * 512 * 2);

    // big region: Wh fp16 [MP x 1024] and G fp16 [MP x 1024] alias (Wh dead before G write)
    f16* big = (f16*)alloc((size_t)MP * 1024 * 2);
    f16* Wh = big;
    f16* G  = big;
    f16* h2 = (f16*)alloc((size_t)MP * 256 * 2);

    hipMemsetAsync(zz, 0, ZZ, stream);

    k_convert<<<1024, 256, 0, stream>>>(W_msg, wmsg, 1024 * 256);
    k_pack_G<<<2048, 256, 0, stream>>>(w_ih, w_hh, wG);
    k_bias<<<4, 256, 0, stream>>>(b_ih, b_hh, bG);
    k_feat<<<MP, 256, 0, stream>>>(feat, ah);

    k_count<<<(EE + 255) / 256, 256, 0, stream>>>(dst, cnt);
    k_scan1<<<SCAN_B, 1024, 0, stream>>>(cnt, rowptr, bsum);
    k_scan2<<<1, 64, 0, stream>>>(bsum);
    k_scan3<<<SCAN_B, 1024, 0, stream>>>(rowptr, bsum, cur);
    k_fill<<<(EE + 255) / 256, 256, 0, stream>>>(src, dst, etype, cur, colpk);

    for (int s = 0; s < 5; ++s) {
        // Wh = h * W_msg^T  [MP x 1024] fp16   (K=256 -> KT=4)
        gemm_f16_o16<<<dim3(8, MP / 128), 256, 0, stream>>>(
            ah + 256, 512, wmsg, 256, b_msg, Wh, 1024, 4);
        k_agg<<<MP, 256, 0, stream>>>(Wh, rowptr, colpk, ah);
        // G = [rsum|zsum|i_n|h_n] fp16, merged per-tile-K GEMM
        gemm_gru<<<dim3(8, MP / 128), 256, 0, stream>>>(ah, wG, bG, G);
        k_gru<<<MP, 256, 0, stream>>>(G, ah);
    }

    k_elu_stats<<<MP / 32, 256, 0, stream>>>(ah, h2, bnsum, bnsq);
    k_prep<<<1, 256, 0, stream>>>(bnsum, bnsq, bn_g, bn_b, gatew, gateb, wp);
    k_gate<<<235, 256, 0, stream>>>(h2, wp, n2g, gate, gmaxenc);
    k_expden<<<(NN + 255) / 256, 256, 0, stream>>>(gate, n2g, gmaxenc, denom);
    k_pool<<<235, 256, 0, stream>>>(h2, gate, denom, n2g, h_g);
    k_cls<<<GG, 256, 0, stream>>>(h_g, bnsum, bnsq, bn_g, bn_b, W1, b1, W2, b2, out);

    (void)in_sizes; (void)n_in; (void)out_size; (void)ws_size;
}

// Round 9
// 1029.863 us; speedup vs baseline: 2.1637x; 1.0489x over previous
//
#include <hip/hip_runtime.h>

#define NN 30000
#define EE 480000
#define HH 256
#define TT 4
#define GG 64
#define CC 10
#define MP 30080   // 235 * 128, padded rows
#define SCAN_B 30  // ceil(NN/1024)
#define STB 120    // stats blocks

typedef unsigned short u16;
typedef unsigned int u32;
typedef _Float16 f16;
typedef f16 half8 __attribute__((ext_vector_type(8)));
typedef f16 half4 __attribute__((ext_vector_type(4)));
typedef float f32x4 __attribute__((ext_vector_type(4)));

// ---------- helpers ----------
__device__ __forceinline__ u32 encf(float x) {       // order-preserving float->uint
    u32 u = __float_as_uint(x);
    return (u & 0x80000000u) ? ~u : (u | 0x80000000u);
}
__device__ __forceinline__ float decf(u32 e) {
    u32 u = (e & 0x80000000u) ? (e ^ 0x80000000u) : ~u;
    return __uint_as_float(u);
}
__device__ __forceinline__ void gl_lds16(const void* g, void* l) {
    __builtin_amdgcn_global_load_lds(
        (const __attribute__((address_space(1))) void*)g,
        (__attribute__((address_space(3))) void*)l, 16, 0, 0);
}

// ---------- conversion / packing kernels ----------
__global__ void k_convert(const float* __restrict__ in, f16* __restrict__ o, int n) {
    int i = blockIdx.x * 256 + threadIdx.x;
    if (i < n) o[i] = (f16)in[i];
}

// packed GRU weight wG [1024 x 512]:
//   rows 0..511  : [w_ih_rz | w_hh_rz]           (K=[0,512))
//   rows 512..767: [w_ih_n  | 0      ]           (K=[0,256))
//   rows 768..1023:[0       | w_hh_n ]           (K=[256,512))
__global__ void k_pack_G(const float* __restrict__ w_ih, const float* __restrict__ w_hh,
                         f16* __restrict__ o) {
    int i = blockIdx.x * 256 + threadIdx.x;   // over 1024*512
    int j = i >> 9, k = i & 511;
    float v;
    if (j < 512)       v = (k < 256) ? w_ih[j * 256 + k] : w_hh[j * 256 + (k - 256)];
    else if (j < 768)  v = (k < 256) ? w_ih[j * 256 + k] : 0.f;
    else               v = (k >= 256) ? w_hh[(j - 256) * 256 + (k - 256)] : 0.f;
    o[i] = (f16)v;
}

__global__ void k_bias(const float* __restrict__ b_ih, const float* __restrict__ b_hh,
                       float* __restrict__ bG) {
    int j = threadIdx.x + blockIdx.x * 256;
    if (j < 512)       bG[j] = b_ih[j] + b_hh[j];
    else if (j < 768)  bG[j] = b_ih[j];
    else if (j < 1024) bG[j] = b_hh[j - 256];
}

// h state -> ah cols 256..511. Padded rows = 0.
__global__ __launch_bounds__(256) void k_feat(const float* __restrict__ feat,
                                              f16* __restrict__ ah) {
    int n = blockIdx.x, c = threadIdx.x;
    float v = (n < NN) ? feat[(size_t)n * HH + c] : 0.f;
    ah[(size_t)n * 512 + 256 + c] = (f16)v;
}

// ---------- CSR build ----------
__global__ void k_count(const int* __restrict__ dst, int* __restrict__ cnt) {
    int e = blockIdx.x * 256 + threadIdx.x;
    if (e < EE) atomicAdd(&cnt[dst[e]], 1);
}

__global__ __launch_bounds__(1024) void k_scan1(const int* __restrict__ cnt,
                                                int* __restrict__ rowptr,
                                                int* __restrict__ bsum) {
    __shared__ int buf[1024];
    int b = blockIdx.x, tid = threadIdx.x;
    int idx = b * 1024 + tid;
    int x = (idx < NN) ? cnt[idx] : 0;
    buf[tid] = x;
    __syncthreads();
    for (int ofs = 1; ofs < 1024; ofs <<= 1) {
        int v = (tid >= ofs) ? buf[tid - ofs] : 0;
        __syncthreads();
        buf[tid] += v;
        __syncthreads();
    }
    if (idx < NN) rowptr[idx] = buf[tid] - x;
    if (tid == 1023) bsum[b] = buf[1023];
}

__global__ void k_scan2(int* __restrict__ bsum) {
    __shared__ int s[SCAN_B];
    int tid = threadIdx.x;
    if (tid < SCAN_B) s[tid] = bsum[tid];
    __syncthreads();
    if (tid == 0) {
        int run = 0;
        for (int i = 0; i < SCAN_B; ++i) { int v = s[i]; s[i] = run; run += v; }
    }
    __syncthreads();
    if (tid < SCAN_B) bsum[tid] = s[tid];
}

__global__ __launch_bounds__(1024) void k_scan3(int* __restrict__ rowptr,
                                                const int* __restrict__ bsum,
                                                int* __restrict__ cur) {
    int b = blockIdx.x, tid = threadIdx.x;
    int idx = b * 1024 + tid;
    if (idx < NN) {
        int v = rowptr[idx] + bsum[b];
        rowptr[idx] = v;
        cur[idx] = v;
    }
    if (idx == 0) rowptr[NN] = EE;
}

__global__ void k_fill(const int* __restrict__ src, const int* __restrict__ dst,
                       const int* __restrict__ et, int* __restrict__ cur,
                       int* __restrict__ colpk) {
    int e = blockIdx.x * 256 + threadIdx.x;
    if (e < EE) {
        int pos = atomicAdd(&cur[dst[e]], 1);
        colpk[pos] = (et[e] << 16) | src[e];
    }
}

// ---------- fp16 MFMA GEMM, BK=64, XOR-swizzled LDS, fp16 output ----------
__global__ __launch_bounds__(256) void gemm_f16_o16(
    const f16* __restrict__ A, int lda,
    const f16* __restrict__ B, int ldb,
    const float* __restrict__ bias, f16* __restrict__ C, int ldc, int KT) {
    __shared__ f16 sA[8192], sB[8192];
    const int tid = threadIdx.x;
    const int lane = tid & 63;
    const int wv = tid >> 6;
    const int wr = wv >> 1, wc = wv & 1;
    const int m0 = blockIdx.y * 128, n0 = blockIdx.x * 128;

    const int ldRow = tid >> 3;
    const int ldK = ((tid & 7) ^ (ldRow & 7)) * 8;
    const f16* aP = A + (size_t)(m0 + ldRow) * lda + ldK;
    const f16* bP = B + (size_t)(n0 + ldRow) * ldb + ldK;
    const size_t rstepA = (size_t)32 * lda;
    const size_t rstepB = (size_t)32 * ldb;

    const int wbyte = (tid & ~63) * 16;
    char* dA = (char*)sA + wbyte;
    char* dB = (char*)sB + wbyte;

    f32x4 acc[4][4];
#pragma unroll
    for (int i = 0; i < 4; i++)
#pragma unroll
        for (int j = 0; j < 4; j++) acc[i][j] = {0.f, 0.f, 0.f, 0.f};

    const int fr = lane & 15;
    const int l7 = lane & 7;
    const int cq = lane >> 4;
    const int p0 = (cq ^ l7) * 8;
    const int p1 = ((cq + 4) ^ l7) * 8;

    for (int kt = 0; kt < KT; ++kt) {
        const int k0 = kt * 64;
        __syncthreads();
        gl_lds16(aP + k0, dA);
        gl_lds16(aP + k0 + rstepA, dA + 4096);
        gl_lds16(aP + k0 + 2 * rstepA, dA + 8192);
        gl_lds16(aP + k0 + 3 * rstepA, dA + 12288);
        gl_lds16(bP + k0, dB);
        gl_lds16(bP + k0 + rstepB, dB + 4096);
        gl_lds16(bP + k0 + 2 * rstepB, dB + 8192);
        gl_lds16(bP + k0 + 3 * rstepB, dB + 12288);
        __syncthreads();

#pragma unroll
        for (int kk = 0; kk < 2; ++kk) {
            const int p = kk ? p1 : p0;
            half8 bh[4];
#pragma unroll
            for (int j = 0; j < 4; j++) {
                int brow = wc * 64 + j * 16 + fr;
                bh[j] = *(const half8*)&sB[brow * 64 + p];
            }
#pragma unroll
            for (int i = 0; i < 4; i++) {
                int arow = wr * 64 + i * 16 + fr;
                half8 ah = *(const half8*)&sA[arow * 64 + p];
#pragma unroll
                for (int j = 0; j < 4; j++)
                    acc[i][j] = __builtin_amdgcn_mfma_f32_16x16x32_f16(ah, bh[j], acc[i][j], 0, 0, 0);
            }
        }
    }

    const int lr = (lane >> 4) * 4;
    const int lc = lane & 15;
#pragma unroll
    for (int j = 0; j < 4; j++) {
        const int col = n0 + wc * 64 + j * 16 + lc;
        const float bj = bias[col];
#pragma unroll
        for (int i = 0; i < 4; i++) {
            const int rb = m0 + wr * 64 + i * 16 + lr;
#pragma unroll
            for (int r = 0; r < 4; r++)
                C[(size_t)(rb + r) * ldc + col] = (f16)(acc[i][j][r] + bj);
        }
    }
}

// merged GRU GEMM: G[MP x 1024] = [a|h] x wG^T, per-tile K-range.
// tiles 0-3: rz (K 0..511); 4-5: i_n (K 0..255); 6-7: h_n (K 256..511)
__global__ __launch_bounds__(256) void gemm_gru(
    const f16* __restrict__ A,
    const f16* __restrict__ B,
    const float* __restrict__ bias, f16* __restrict__ C) {
    __shared__ f16 sA[8192], sB[8192];
    const int tid = threadIdx.x;
    const int lane = tid & 63;
    const int wv = tid >> 6;
    const int wr = wv >> 1, wc = wv & 1;
    const int m0 = blockIdx.y * 128, n0 = blockIdx.x * 128;
    const int kt0 = (blockIdx.x >= 6) ? 4 : 0;
    const int kt1 = (blockIdx.x >= 4 && blockIdx.x < 6) ? 4 : 8;

    const int ldRow = tid >> 3;
    const int ldK = ((tid & 7) ^ (ldRow & 7)) * 8;
    const f16* aP = A + (size_t)(m0 + ldRow) * 512 + ldK;
    const f16* bP = B + (size_t)(n0 + ldRow) * 512 + ldK;
    const size_t rstep = (size_t)32 * 512;

    const int wbyte = (tid & ~63) * 16;
    char* dA = (char*)sA + wbyte;
    char* dB = (char*)sB + wbyte;

    f32x4 acc[4][4];
#pragma unroll
    for (int i = 0; i < 4; i++)
#pragma unroll
        for (int j = 0; j < 4; j++) acc[i][j] = {0.f, 0.f, 0.f, 0.f};

    const int fr = lane & 15;
    const int l7 = lane & 7;
    const int cq = lane >> 4;
    const int p0 = (cq ^ l7) * 8;
    const int p1 = ((cq + 4) ^ l7) * 8;

    for (int kt = kt0; kt < kt1; ++kt) {
        const int k0 = kt * 64;
        __syncthreads();
        gl_lds16(aP + k0, dA);
        gl_lds16(aP + k0 + rstep, dA + 4096);
        gl_lds16(aP + k0 + 2 * rstep, dA + 8192);
        gl_lds16(aP + k0 + 3 * rstep, dA + 12288);
        gl_lds16(bP + k0, dB);
        gl_lds16(bP + k0 + rstep, dB + 4096);
        gl_lds16(bP + k0 + 2 * rstep, dB + 8192);
        gl_lds16(bP + k0 + 3 * rstep, dB + 12288);
        __syncthreads();

#pragma unroll
        for (int kk = 0; kk < 2; ++kk) {
            const int p = kk ? p1 : p0;
            half8 bh[4];
#pragma unroll
            for (int j = 0; j < 4; j++) {
                int brow = wc * 64 + j * 16 + fr;
                bh[j] = *(const half8*)&sB[brow * 64 + p];
            }
#pragma unroll
            for (int i = 0; i < 4; i++) {
                int arow = wr * 64 + i * 16 + fr;
                half8 ah = *(const half8*)&sA[arow * 64 + p];
#pragma unroll
                for (int j = 0; j < 4; j++)
                    acc[i][j] = __builtin_amdgcn_mfma_f32_16x16x32_f16(ah, bh[j], acc[i][j], 0, 0, 0);
            }
        }
    }

    const int lr = (lane >> 4) * 4;
    const int lc = lane & 15;
#pragma unroll
    for (int j = 0; j < 4; j++) {
        const int col = n0 + wc * 64 + j * 16 + lc;
        const float bj = bias[col];
#pragma unroll
        for (int i = 0; i < 4; i++) {
            const int rb = m0 + wr * 64 + i * 16 + lr;
#pragma unroll
            for (int r = 0; r < 4; r++)
                C[(size_t)(rb + r) * 1024 + col] = (f16)(acc[i][j][r] + bj);
        }
    }
}

// ---------- per-dst aggregation (pull via CSR, latency-hidden) -> ah cols 0..255 ----------
__global__ __launch_bounds__(256) void k_agg(const f16* __restrict__ Wh,
                                             const int* __restrict__ rowptr,
                                             const int* __restrict__ colpk,
                                             f16* __restrict__ ah) {
    __shared__ int spk[256];
    __shared__ float4 sacc[3][64];
    const int n = blockIdx.x;
    const int tid = threadIdx.x;
    const int col4 = tid & 63;
    const int strip = tid >> 6;
    float4 acc = {0.f, 0.f, 0.f, 0.f};

    if (n < NN) {
        const int e0 = rowptr[n], e1 = rowptr[n + 1];
        for (int base = e0; base < e1; base += 256) {
            const int chunk = min(256, e1 - base);
            __syncthreads();
            if (tid < chunk) spk[tid] = colpk[base + tid];
            __syncthreads();
            int i = strip;
            for (; i + 4 < chunk; i += 8) {
                const int pk0 = spk[i], pk1 = spk[i + 4];
                const half4 v0 = *(const half4*)&Wh[(size_t)(pk0 & 0xFFFF) * 1024 + (pk0 >> 16) * 256 + col4 * 4];
                const half4 v1 = *(const half4*)&Wh[(size_t)(pk1 & 0xFFFF) * 1024 + (pk1 >> 16) * 256 + col4 * 4];
                acc.x += (float)v0.x + (float)v1.x;
                acc.y += (float)v0.y + (float)v1.y;
                acc.z += (float)v0.z + (float)v1.z;
                acc.w += (float)v0.w + (float)v1.w;
            }
            for (; i < chunk; i += 4) {
                const int pk = spk[i];
                const half4 v = *(const half4*)&Wh[(size_t)(pk & 0xFFFF) * 1024 + (pk >> 16) * 256 + col4 * 4];
                acc.x += (float)v.x;
                acc.y += (float)v.y;
                acc.z += (float)v.z;
                acc.w += (float)v.w;
            }
        }
    }
    if (strip) sacc[strip - 1][col4] = acc;
    __syncthreads();
    if (strip == 0 && n < NN) {
        const float4 t0 = sacc[0][col4], t1 = sacc[1][col4], t2 = sacc[2][col4];
        half4 o;
        o.x = (f16)(acc.x + t0.x + t1.x + t2.x);
        o.y = (f16)(acc.y + t0.y + t1.y + t2.y);
        o.z = (f16)(acc.z + t0.z + t1.z + t2.z);
        o.w = (f16)(acc.w + t0.w + t1.w + t2.w);
        *(half4*)&ah[(size_t)n * 512 + col4 * 4] = o;
    }
}

// ---------- GRU cell elementwise: G = [rsum|zsum|i_n|h_n] fp16 ----------
__global__ __launch_bounds__(256) void k_gru(const f16* __restrict__ G,
                                             f16* __restrict__ ah) {
    int n = blockIdx.x, c = threadIdx.x;
    size_t b = (size_t)n * 1024 + c;
    float rsum = (float)G[b], zsum = (float)G[b + 256];
    float inn = (float)G[b + 512], hn = (float)G[b + 768];
    float r = 1.f / (1.f + expf(-rsum));
    float z = 1.f / (1.f + expf(-zsum));
    float nn = tanhf(inn + r * hn);
    size_t i = (size_t)n * 512 + 256 + c;
    float hv = (float)ah[i];
    float o = (1.f - z) * nn + z * hv;
    ah[i] = (f16)o;
}

// ---------- BN stats over elu(h): per-block partials, NO atomics ----------
__global__ __launch_bounds__(256) void k_stats(const f16* __restrict__ ah,
                                               float* __restrict__ pbuf) {
    __shared__ float4 ssum[3][64], ssq[3][64];
    int tid = threadIdx.x, lane = tid & 63, w = tid >> 6;
    int c4 = lane * 4;
    float4 s = {0.f, 0.f, 0.f, 0.f}, q = {0.f, 0.f, 0.f, 0.f};
    for (int n = blockIdx.x * 4 + w; n < NN; n += STB * 4) {
        half4 v = *(const half4*)&ah[(size_t)n * 512 + 256 + c4];
        float ex = (float)v.x, ey = (float)v.y, ez = (float)v.z, ew = (float)v.w;
        ex = ex > 0.f ? ex : expm1f(ex);
        ey = ey > 0.f ? ey : expm1f(ey);
        ez = ez > 0.f ? ez : expm1f(ez);
        ew = ew > 0.f ? ew : expm1f(ew);
        s.x += ex; s.y += ey; s.z += ez; s.w += ew;
        q.x += ex * ex; q.y += ey * ey; q.z += ez * ez; q.w += ew * ew;
    }
    if (w) { ssum[w - 1][lane] = s; ssq[w - 1][lane] = q; }
    __syncthreads();
    if (w == 0) {
#pragma unroll
        for (int k = 0; k < 3; ++k) {
            float4 a = ssum[k][lane], b = ssq[k][lane];
            s.x += a.x; s.y += a.y; s.z += a.z; s.w += a.w;
            q.x += b.x; q.y += b.y; q.z += b.z; q.w += b.w;
        }
        *(float4*)&pbuf[blockIdx.x * 512 + c4] = s;
        *(float4*)&pbuf[blockIdx.x * 512 + 256 + c4] = q;
    }
}

// ---------- reduce partials + fold BN affine into gate weights ----------
// wp[0..255] scaled weights, wp[256] = const; also writes bnsum/bnsq for k_cls.
__global__ __launch_bounds__(256) void k_prep(const float* __restrict__ pbuf,
                                              const float* __restrict__ gamma,
                                              const float* __restrict__ beta,
                                              const float* __restrict__ gate_w,
                                              const float* __restrict__ gate_b,
                                              float* __restrict__ wp,
                                              float* __restrict__ bnsum,
                                              float* __restrict__ bnsq) {
    __shared__ float red[256];
    int c = threadIdx.x;
    float s = 0.f, q = 0.f;
    for (int b = 0; b < STB; ++b) {
        s += pbuf[b * 512 + c];
        q += pbuf[b * 512 + 256 + c];
    }
    bnsum[c] = s;
    bnsq[c] = q;
    float mu = s * (1.f / NN);
    float var = q * (1.f / NN) - mu * mu;
    float rs = rsqrtf(var + 1e-5f);
    float gm = gamma[c], w = gate_w[c];
    wp[c] = rs * gm * w;
    red[c] = (beta[c] - mu * rs * gm) * w;
    __syncthreads();
    for (int st = 128; st > 0; st >>= 1) {
        if (c < st) red[c] += red[c + st];
        __syncthreads();
    }
    if (c == 0) wp[256] = red[0] + gate_b[0];
}

// ---------- gate score: elu on the fly, wave dots, LDS-staged segment max ----------
__global__ __launch_bounds__(256) void k_gate(const f16* __restrict__ ah,
                                              const float* __restrict__ wp,
                                              const int* __restrict__ n2g,
                                              float* __restrict__ gate,
                                              u32* __restrict__ gmaxenc) {
    __shared__ u32 smax[64];
    int tid = threadIdx.x;
    if (tid < 64) smax[tid] = 0;
    __syncthreads();
    int lane = tid & 63, wv = tid >> 6;
    int base = blockIdx.x * 128 + wv * 32;
    float4 w = ((const float4*)wp)[lane];
    float wc = wp[256];
    for (int k = 0; k < 32; ++k) {
        int n = base + k;
        if (n >= NN) break;
        half4 v = *(const half4*)&ah[(size_t)n * 512 + 256 + lane * 4];
        float ex = (float)v.x, ey = (float)v.y, ez = (float)v.z, ew = (float)v.w;
        ex = ex > 0.f ? ex : expm1f(ex);
        ey = ey > 0.f ? ey : expm1f(ey);
        ez = ez > 0.f ? ez : expm1f(ez);
        ew = ew > 0.f ? ew : expm1f(ew);
        float s = ex * w.x + ey * w.y + ez * w.z + ew * w.w;
#pragma unroll
        for (int off = 32; off; off >>= 1) s += __shfl_down(s, off);
        if (lane == 0) {
            float gt = s + wc;
            gate[n] = gt;
            atomicMax(&smax[n2g[n]], encf(gt));
        }
    }
    __syncthreads();
    if (tid < 64 && smax[tid]) atomicMax(&gmaxenc[tid], smax[tid]);
}

// ---------- exp + denom (LDS-staged segment sum) ----------
__global__ void k_expden(float* __restrict__ gate,
                         const int* __restrict__ n2g,
                         const u32* __restrict__ gmaxenc,
                         float* __restrict__ denom) {
    __shared__ float ssum[64];
    int tid = threadIdx.x;
    if (tid < 64) ssum[tid] = 0.f;
    __syncthreads();
    int n = blockIdx.x * 256 + tid;
    if (n < NN) {
        int g = n2g[n];
        float e = expf(gate[n] - decf(gmaxenc[g]));
        gate[n] = e;
        atomicAdd(&ssum[g], e);
    }
    __syncthreads();
    if (tid < 64 && ssum[tid] != 0.f) atomicAdd(&denom[tid], ssum[tid]);
}

// ---------- attention pooling, elu on the fly (n2g sorted; flush on change) ----------
__global__ __launch_bounds__(256) void k_pool(const f16* __restrict__ ah,
                                              const float* __restrict__ gate,
                                              const float* __restrict__ denom,
                                              const int* __restrict__ n2g,
                                              float* __restrict__ h_g) {
    int c = threadIdx.x;
    int r0 = blockIdx.x * 32, r1 = min(r0 + 32, NN);
    int gcur = -1;
    float accv = 0.f, inv = 0.f;
    for (int n = r0; n < r1; ++n) {
        int g = n2g[n];
        if (g != gcur) {
            if (gcur >= 0) atomicAdd(&h_g[gcur * HH + c], accv);
            gcur = g;
            accv = 0.f;
            inv = 1.f / denom[g];
        }
        float x = (float)ah[(size_t)n * 512 + 256 + c];
        x = x > 0.f ? x : expm1f(x);
        accv += gate[n] * inv * x;
    }
    if (gcur >= 0) atomicAdd(&h_g[gcur * HH + c], accv);
}

// ---------- classifier (applies BN affine to pooled vector) ----------
__global__ __launch_bounds__(256) void k_cls(const float* __restrict__ h_g,
                                             const float* __restrict__ bnsum,
                                             const float* __restrict__ bnsq,
                                             const float* __restrict__ gamma,
                                             const float* __restrict__ beta,
                                             const float* __restrict__ W1,
                                             const float* __restrict__ b1,
                                             const float* __restrict__ W2,
                                             const float* __restrict__ b2,
                                             float* __restrict__ out) {
    __shared__ float hg[256];
    __shared__ float x1[128];
    int g = blockIdx.x, tid = threadIdx.x;
    float mu = bnsum[tid] * (1.f / NN);
    float var = bnsq[tid] * (1.f / NN) - mu * mu;
    hg[tid] = (h_g[g * HH + tid] - mu) * rsqrtf(var + 1e-5f) * gamma[tid] + beta[tid];
    __syncthreads();
    if (tid < 128) {
        const float* w = W1 + tid * 256;
        float s = b1[tid];
#pragma unroll 8
        for (int c = 0; c < 256; ++c) s += hg[c] * w[c];
        x1[tid] = fmaxf(s, 0.f);
    }
    __syncthreads();
    if (tid < 10) {
        const float* w = W2 + tid * 128;
        float s = b2[tid];
        for (int j = 0; j < 128; ++j) s += x1[j] * w[j];
        out[g * CC + tid] = s;
    }
}

// =======================================================================
extern "C" void kernel_launch(void* const* d_in, const int* in_sizes, int n_in,
                              void* d_out, int out_size, void* d_ws, size_t ws_size,
                              hipStream_t stream) {
    const float* feat  = (const float*)d_in[0];
    const int*   src   = (const int*)d_in[1];
    const int*   dst   = (const int*)d_in[2];
    const int*   etype = (const int*)d_in[3];
    const int*   n2g   = (const int*)d_in[4];
    const float* W_msg = (const float*)d_in[5];
    const float* b_msg = (const float*)d_in[6];
    const float* w_ih  = (const float*)d_in[7];
    const float* w_hh  = (const float*)d_in[8];
    const float* b_ih  = (const float*)d_in[9];
    const float* b_hh  = (const float*)d_in[10];
    const float* bn_g  = (const float*)d_in[11];
    const float* bn_b  = (const float*)d_in[12];
    const float* gatew = (const float*)d_in[13];
    const float* gateb = (const float*)d_in[14];
    const float* W1    = (const float*)d_in[15];
    const float* b1    = (const float*)d_in[16];
    const float* W2    = (const float*)d_in[17];
    const float* b2    = (const float*)d_in[18];
    float* out = (float*)d_out;

    char* ws = (char*)d_ws;
    size_t off = 0;
    auto alloc = [&](size_t bytes) -> char* {
        char* p = ws + off;
        off += (bytes + 255) & ~(size_t)255;
        return p;
    };

    // zero zone (single memset): cnt | denom | gmaxenc | h_g
    const size_t ZZ = (size_t)(NN + 64 + 64 + GG * HH) * 4;
    char* zz = alloc(ZZ);
    int*   cnt     = (int*)zz;
    float* denom   = (float*)(zz + (size_t)NN * 4);
    u32*   gmaxenc = (u32*)(denom + 64);
    float* h_g     = (float*)(gmaxenc + 64);

    int* rowptr = (int*)alloc((NN + 1) * 4);
    int* cur    = (int*)alloc(NN * 4);
    int* bsum   = (int*)alloc(SCAN_B * 4);
    int* colpk  = (int*)alloc((size_t)EE * 4);
    float* gate = (float*)alloc(NN * 4);
    float* wp   = (float*)alloc(260 * 4);
    float* bG   = (float*)alloc(1024 * 4);
    float* pbuf = (float*)alloc((size_t)STB * 512 * 4);
    float* bnsum = (float*)alloc(256 * 4);
    float* bnsq  = (float*)alloc(256 * 4);

    // interleaved node state: cols 0..255 = a, cols 256..511 = h (fp16)
    f16* ah = (f16*)alloc((size_t)MP * 512 * 2);

    f16* wmsg = (f16*)alloc((size_t)1024 * 256 * 2);
    f16* wG   = (f16*)alloc((size_t)1024 * 512 * 2);

    // big region: Wh fp16 [MP x 1024] and G fp16 [MP x 1024] alias
    f16* big = (f16*)alloc((size_t)MP * 1024 * 2);
    f16* Wh = big;
    f16* G  = big;

    hipMemsetAsync(zz, 0, ZZ, stream);

    k_convert<<<1024, 256, 0, stream>>>(W_msg, wmsg, 1024 * 256);
    k_pack_G<<<2048, 256, 0, stream>>>(w_ih, w_hh, wG);
    k_bias<<<4, 256, 0, stream>>>(b_ih, b_hh, bG);
    k_feat<<<MP, 256, 0, stream>>>(feat, ah);

    k_count<<<(EE + 255) / 256, 256, 0, stream>>>(dst, cnt);
    k_scan1<<<SCAN_B, 1024, 0, stream>>>(cnt, rowptr, bsum);
    k_scan2<<<1, 64, 0, stream>>>(bsum);
    k_scan3<<<SCAN_B, 1024, 0, stream>>>(rowptr, bsum, cur);
    k_fill<<<(EE + 255) / 256, 256, 0, stream>>>(src, dst, etype, cur, colpk);

    for (int s = 0; s < 5; ++s) {
        // Wh = h * W_msg^T  [MP x 1024] fp16   (K=256 -> KT=4)
        gemm_f16_o16<<<dim3(8, MP / 128), 256, 0, stream>>>(
            ah + 256, 512, wmsg, 256, b_msg, Wh, 1024, 4);
        k_agg<<<MP, 256, 0, stream>>>(Wh, rowptr, colpk, ah);
        // G = [rsum|zsum|i_n|h_n] fp16, merged per-tile-K GEMM
        gemm_gru<<<dim3(8, MP / 128), 256, 0, stream>>>(ah, wG, bG, G);
        k_gru<<<MP, 256, 0, stream>>>(G, ah);
    }

    k_stats<<<STB, 256, 0, stream>>>(ah, pbuf);
    k_prep<<<1, 256, 0, stream>>>(pbuf, bn_g, bn_b, gatew, gateb, wp, bnsum, bnsq);
    k_gate<<<235, 256, 0, stream>>>(ah, wp, n2g, gate, gmaxenc);
    k_expden<<<(NN + 255) / 256, 256, 0, stream>>>(gate, n2g, gmaxenc, denom);
    k_pool<<<MP / 32, 256, 0, stream>>>(ah, gate, denom, n2g, h_g);
    k_cls<<<GG, 256, 0, stream>>>(h_g, bnsum, bnsq, bn_g, bn_b, W1, b1, W2, b2, out);

    (void)in_sizes; (void)n_in; (void)out_size; (void)ws_size;
}